// Round 5
// baseline (283.928 us; speedup 1.0000x reference)
//
#include <hip/hip_runtime.h>
#include <hip/hip_bf16.h>

typedef __attribute__((ext_vector_type(8))) short short8;
typedef __attribute__((ext_vector_type(4))) float f32x4;
typedef __attribute__((ext_vector_type(16))) float f32x16;

#define N_EMBED 2048
#define N_HEAD 16
#define D_KV 128
#define D_C 64
#define D_R 64
#define D_H 128
#define BB 2
#define SS 2048
#define NTOK (BB*SS)          // 4096

__device__ __forceinline__ unsigned short f2bf(float f) {
    unsigned int b = __builtin_bit_cast(unsigned int, f);
    b += 0x7fffu + ((b >> 16) & 1u);
    return (unsigned short)(b >> 16);
}
__device__ __forceinline__ float bf2f(unsigned short u) {
    unsigned int b = ((unsigned int)u) << 16;
    return __builtin_bit_cast(float, b);
}

#define GLOAD_LDS16(gsrc, ldst) __builtin_amdgcn_global_load_lds( \
    (const __attribute__((address_space(1))) void*)(gsrc), \
    (__attribute__((address_space(3))) void*)(ldst), 16, 0, 0)

// ---------------- conversion / layout kernels ----------------

__global__ void conv_f32_bf16(const float* __restrict__ in, unsigned short* __restrict__ out, int n) {
    int i = (blockIdx.x * 256 + threadIdx.x) * 4;
    if (i >= n) return;
    float4 v = *(const float4*)(in + i);
    ushort4 o;
    o.x = f2bf(v.x); o.y = f2bf(v.y); o.z = f2bf(v.z); o.w = f2bf(v.w);
    *(ushort4*)(out + i) = o;
}

// Wcat_T [320][2048]
__global__ void build_wcat(const float* __restrict__ Wdkv, const float* __restrict__ Wdq,
                           const float* __restrict__ Wkr, unsigned short* __restrict__ out) {
    int i = blockIdx.x * 256 + threadIdx.x;
    int n = i >> 11, k = i & 2047;
    float v;
    if (n < 128)      v = Wdkv[k * 128 + n];
    else if (n < 256) v = Wdq[k * 128 + (n - 128)];
    else              v = Wkr[k * 64 + (n - 256)];
    out[i] = f2bf(v);
}

// Wq_T [2048][128]
__global__ void build_wq(const float* __restrict__ Wqc, const float* __restrict__ Wqr,
                         unsigned short* __restrict__ out) {
    int i = blockIdx.x * 256 + threadIdx.x;
    int n = i >> 7, k = i & 127;
    int h = n >> 7, c = n & 127;
    float v = (c < 64) ? Wqc[(h * 128 + k) * 64 + c] : Wqr[(h * 128 + k) * 64 + (c - 64)];
    out[i] = f2bf(v);
}

// Wk_T [1024][128]
__global__ void build_wk(const float* __restrict__ Wuk, unsigned short* __restrict__ out) {
    int i = blockIdx.x * 256 + threadIdx.x;
    int n = i >> 7, k = i & 127;
    int h = n >> 6, c = n & 63;
    out[i] = f2bf(Wuk[(h * 128 + k) * 64 + c]);
}

// WuvT [16][128][128]
__global__ void build_wuvT(const float* __restrict__ Wuv, unsigned short* __restrict__ out) {
    int i = blockIdx.x * 256 + threadIdx.x;
    int h = i >> 14, d = (i >> 7) & 127, k = i & 127;
    out[i] = f2bf(Wuv[(h * 128 + k) * 128 + d]);
}

// Wo_T [2048][2048] via LDS-tiled transpose
__global__ __launch_bounds__(256) void build_wo(const float* __restrict__ Wo, unsigned short* __restrict__ out) {
    __shared__ float tile[64][65];
    const int k0 = blockIdx.x * 64, n0 = blockIdx.y * 64;
    const int tid = threadIdx.x;
    const int tr = tid >> 4, tc = (tid & 15) * 4;
#pragma unroll
    for (int it = 0; it < 4; ++it) {
        int r = it * 16 + tr;
        float4 v = *(const float4*)(Wo + (size_t)(k0 + r) * 2048 + n0 + tc);
        tile[r][tc] = v.x; tile[r][tc + 1] = v.y; tile[r][tc + 2] = v.z; tile[r][tc + 3] = v.w;
    }
    __syncthreads();
#pragma unroll
    for (int it = 0; it < 4; ++it) {
        int r = it * 16 + tr;
        ushort4 o;
        o.x = f2bf(tile[tc][r]); o.y = f2bf(tile[tc + 1][r]);
        o.z = f2bf(tile[tc + 2][r]); o.w = f2bf(tile[tc + 3][r]);
        *(ushort4*)(out + (size_t)(n0 + r) * 2048 + k0 + tc) = o;
    }
}

// ---------------- rope ----------------

#define ROPE_COEF (-0.28782313662425575f)  // -ln(10000)/32

__global__ void rope_k_kernel(unsigned short* __restrict__ g1) {
    int i = blockIdx.x * 256 + threadIdx.x;   // NTOK*32
    int j = i & 31, row = i >> 5;
    int pos = row & (SS - 1);
    float freq = __expf(ROPE_COEF * (float)j);
    float a = (float)pos * freq;
    float s, c;
    __sincosf(a, &s, &c);
    unsigned short* p = g1 + (size_t)row * 320 + 256 + 2 * j;
    float x0 = bf2f(p[0]), x1 = bf2f(p[1]);
    p[0] = f2bf(x0 * c - x1 * s);
    p[1] = f2bf(x0 * s + x1 * c);
}

__global__ void rope_q_kernel(unsigned short* __restrict__ q) {
    int i = blockIdx.x * 256 + threadIdx.x;   // NTOK*16*32
    int j = i & 31, h = (i >> 5) & 15, row = i >> 9;
    int pos = row & (SS - 1);
    float freq = __expf(ROPE_COEF * (float)j);
    float a = (float)pos * freq;
    float s, c;
    __sincosf(a, &s, &c);
    unsigned short* p = q + (size_t)row * 2048 + h * 128 + 64 + 2 * j;
    float x0 = bf2f(p[0]), x1 = bf2f(p[1]);
    p[0] = f2bf(x0 * c - x1 * s);
    p[1] = f2bf(x0 * s + x1 * c);
}

// ---------------- GEMM (2-phase dbuf): C[M,N] = A[M,K] * Bt[N,K]^T ----------------

__device__ __forceinline__ void store_c(float* p, float v) { *p = v; }
__device__ __forceinline__ void store_c(unsigned short* p, float v) { *p = f2bf(v); }

template <int BN, typename CT>
__global__ __launch_bounds__(256) void gemm_bf16_kernel(
    const unsigned short* __restrict__ A, int lda,
    const unsigned short* __restrict__ Bt, int ldb,
    CT* __restrict__ C, int ldc,
    int M, int N, int K) {
    constexpr int BM = 128, BK = 32;
    __shared__ __align__(16) unsigned short As[2][BM][BK];
    __shared__ __align__(16) unsigned short Bs[2][BN][BK];
    constexpr int WN = BN / 2;
    constexpr int FM = 4, FN = WN / 16;
    const int tid = threadIdx.x, wave = tid >> 6, lane = tid & 63;
    const int wr = wave >> 1, wc = wave & 1;
    const int lg = lane >> 4, lr = lane & 15;
    const int m0 = blockIdx.y * BM, n0 = blockIdx.x * BN;

    f32x4 acc[FM][FN] = {};

    auto stage = [&](int k0, int buf) {
#pragma unroll
        for (int it = 0; it < (BM * BK) / 2048; ++it) {
            int e = (tid + it * 256) * 8;
            GLOAD_LDS16(A + (size_t)(m0 + (e >> 5)) * lda + k0 + (e & 31), &As[buf][0][0] + e);
        }
#pragma unroll
        for (int it = 0; it < (BN * BK) / 2048; ++it) {
            int e = (tid + it * 256) * 8;
            GLOAD_LDS16(Bt + (size_t)(n0 + (e >> 5)) * ldb + k0 + (e & 31), &Bs[buf][0][0] + e);
        }
    };

    const int nk = K / BK;
    stage(0, 0);
    __syncthreads();
    for (int t = 0; t < nk; ++t) {
        const int cur = t & 1;
        if (t + 1 < nk) stage((t + 1) * BK, cur ^ 1);   // overlaps compute(t)
        short8 af[FM], bfr[FN];
#pragma unroll
        for (int i = 0; i < FM; i++) af[i] = *(const short8*)&As[cur][wr * 64 + i * 16 + lr][lg * 8];
#pragma unroll
        for (int j = 0; j < FN; j++) bfr[j] = *(const short8*)&Bs[cur][wc * WN + j * 16 + lr][lg * 8];
#pragma unroll
        for (int i = 0; i < FM; i++)
#pragma unroll
            for (int j = 0; j < FN; j++)
                acc[i][j] = __builtin_amdgcn_mfma_f32_16x16x32_bf16(af[i], bfr[j], acc[i][j], 0, 0, 0);
        __syncthreads();   // drains stage(t+1) loads
    }
#pragma unroll
    for (int i = 0; i < FM; i++)
#pragma unroll
        for (int j = 0; j < FN; j++)
#pragma unroll
            for (int r = 0; r < 4; r++) {
                int row = m0 + wr * 64 + i * 16 + lg * 4 + r;
                int col = n0 + wc * WN + j * 16 + lr;
                store_c(&C[(size_t)row * ldc + col], acc[i][j][r]);
            }
}

// Batched GEMM producing transposed V: v_t[bh][d][s]
__global__ __launch_bounds__(256) void gemm_vt_kernel(
    const unsigned short* __restrict__ WuvT,   // [16][128][128]
    const unsigned short* __restrict__ g1,     // [NTOK][320], c_kv cols 0..127
    unsigned short* __restrict__ v_t) {        // [32][128][2048]
    constexpr int BK = 32;
    __shared__ __align__(16) unsigned short As[2][128][BK];
    __shared__ __align__(16) unsigned short Bs[2][128][BK];
    const int tid = threadIdx.x, wave = tid >> 6, lane = tid & 63;
    const int wr = wave >> 1, wc = wave & 1;
    const int lg = lane >> 4, lr = lane & 15;
    const int n0 = blockIdx.x * 128;
    const int bh = blockIdx.y, b = bh >> 4, h = bh & 15;
    const unsigned short* A = WuvT + (size_t)h * 16384;
    const unsigned short* Bt = g1 + (size_t)(b * SS) * 320;
    unsigned short* C = v_t + (size_t)bh * 128 * 2048;

    f32x4 acc[4][4] = {};
    auto stage = [&](int k0, int buf) {
#pragma unroll
        for (int it = 0; it < 2; ++it) {
            int e = (tid + it * 256) * 8;
            GLOAD_LDS16(A + (size_t)(e >> 5) * 128 + k0 + (e & 31), &As[buf][0][0] + e);
        }
#pragma unroll
        for (int it = 0; it < 2; ++it) {
            int e = (tid + it * 256) * 8;
            GLOAD_LDS16(Bt + (size_t)(n0 + (e >> 5)) * 320 + k0 + (e & 31), &Bs[buf][0][0] + e);
        }
    };
    stage(0, 0);
    __syncthreads();
    for (int t = 0; t < 4; ++t) {
        const int cur = t & 1;
        if (t + 1 < 4) stage((t + 1) * BK, cur ^ 1);
        short8 af[4], bfr[4];
#pragma unroll
        for (int i = 0; i < 4; i++) af[i] = *(const short8*)&As[cur][wr * 64 + i * 16 + lr][lg * 8];
#pragma unroll
        for (int j = 0; j < 4; j++) bfr[j] = *(const short8*)&Bs[cur][wc * 64 + j * 16 + lr][lg * 8];
#pragma unroll
        for (int i = 0; i < 4; i++)
#pragma unroll
            for (int j = 0; j < 4; j++)
                acc[i][j] = __builtin_amdgcn_mfma_f32_16x16x32_bf16(af[i], bfr[j], acc[i][j], 0, 0, 0);
        __syncthreads();
    }
#pragma unroll
    for (int i = 0; i < 4; i++)
#pragma unroll
        for (int j = 0; j < 4; j++)
#pragma unroll
            for (int r = 0; r < 4; r++) {
                int row = wr * 64 + i * 16 + lg * 4 + r;
                int col = n0 + wc * 64 + j * 16 + lr;
                store_c(&C[(size_t)row * 2048 + col], acc[i][j][r]);
            }
}

// ---------------- flash attention v5: dual q-tile (complementary pair) per block ----------------
// grid 256 (1 block/CU). Block owns q-tiles qb_lo=pr and qb_hi=15-pr for one bh:
// one K/V staging stream serves both -> every block = 34 tile-computes (perfectly
// balanced) + nt_hi stage-tiles. 4 waves x 32 q-rows per tile.
__global__ __launch_bounds__(256, 1) void mla_attn_kernel(
    const unsigned short* __restrict__ q_all,   // [NTOK][2048] roped
    const unsigned short* __restrict__ k_all,   // [NTOK][1024] knope per head
    const unsigned short* __restrict__ g1,      // [NTOK][320], roped k_r at 256
    const unsigned short* __restrict__ v_t,     // [32][128][2048]
    unsigned short* __restrict__ attn_out) {    // [NTOK][2048]
    __shared__ __align__(16) char smem[69632];
    auto Ks = (unsigned short (*)[64][128])smem;            // [2][64][128], chunk-swizzled
    auto Vs = (unsigned short (*)[128][72])(smem + 32768);  // [2][128][72]

    const int id = blockIdx.x;
    const int xcd = id & 7, s = id >> 3;
    const int pr = s & 7;                      // pair index
    const int bh = xcd * 4 + (s >> 3);         // 4 heads per XCD, 8 pair-blocks each
    const int b = bh >> 4, h = bh & 15;
    const int qb_hi = 15 - pr;
    const int nt = 2 * qb_hi + 2;              // stage tiles (= hi tile count)
    const int nt_lo = 2 * pr + 2;
    const int tid = threadIdx.x, wave = tid >> 6, lane = tid & 63;
    const int ql = lane & 31, hb = lane >> 5;
    const int q0w_hi = qb_hi * 128 + wave * 32, qg_hi = q0w_hi + ql;
    const int q0w_lo = pr * 128 + wave * 32,  qg_lo = q0w_lo + ql;
    const int kvB = b * SS;
    const float sc2 = 0.12751744f;   // (1/sqrt(128)) * log2(e)
    const int xh = ql & 7;

    // Q B-operand frags for both tiles: col=q (lane-owned), k = 16s + 8*hb + j
    short8 qfh[8], qfl[8];
    {
        const unsigned short* qp = q_all + (size_t)(kvB + qg_hi) * 2048 + h * 128 + hb * 8;
#pragma unroll
        for (int ss = 0; ss < 8; ++ss) qfh[ss] = *(const short8*)(qp + 16 * ss);
        const unsigned short* qp2 = q_all + (size_t)(kvB + qg_lo) * 2048 + h * 128 + hb * 8;
#pragma unroll
        for (int ss = 0; ss < 8; ++ss) qfl[ss] = *(const short8*)(qp2 + 16 * ss);
    }

    f32x16 oh[4] = {}, ol[4] = {};
    float mh_raw = -3e38f, mh_b = 0.f, lh = 0.f;
    float ml_raw = -3e38f, ml_b = 0.f, ll = 0.f;
    uint4 vreg[4];

    auto stageK = [&](int t, int bufi) {
#pragma unroll
        for (int it = 0; it < 4; ++it) {
            int r = (tid >> 4) + it * 16;
            int sc = (tid & 15) ^ (r & 7);
            const unsigned short* src = (sc < 8)
                ? k_all + (size_t)(kvB + t * 64 + r) * 1024 + h * 64 + sc * 8
                : g1 + (size_t)(kvB + t * 64 + r) * 320 + 256 + (sc - 8) * 8;
            GLOAD_LDS16(src, &Ks[bufi][0][0] + tid * 8 + it * 2048);
        }
    };
    auto loadV = [&](int t) {
#pragma unroll
        for (int it = 0; it < 4; ++it) {
            int e = tid * 8 + it * 2048;
            vreg[it] = *(const uint4*)(v_t + ((size_t)bh * 128 + (e >> 6)) * 2048 + t * 64 + (e & 63));
        }
    };
    auto writeV = [&](int bufi) {
#pragma unroll
        for (int it = 0; it < 4; ++it) {
            int e = tid * 8 + it * 2048;
            *(uint4*)&Vs[bufi][e >> 6][e & 63] = vreg[it];
        }
    };

    // one tile-compute against staged buffer `cur`
    auto compute = [&](int t, int cur, f32x16 (&o)[4], float& m_raw, float& mb, float& l_r,
                       short8 (&qf)[8], int q0w, int qg) {
        // ---- S^T = K * Q ----
        f32x16 p0 = {}, p1 = {};
        __builtin_amdgcn_s_setprio(1);
#pragma unroll
        for (int ss = 0; ss < 8; ++ss) {
            int pc = (((2 * ss + hb) ^ xh) << 3);   // swizzled chunk
            short8 k0 = *(const short8*)&Ks[cur][ql][pc];
            short8 k1 = *(const short8*)&Ks[cur][32 + ql][pc];
            p0 = __builtin_amdgcn_mfma_f32_32x32x16_bf16(k0, qf[ss], p0, 0, 0, 0);
            p1 = __builtin_amdgcn_mfma_f32_32x32x16_bf16(k1, qf[ss], p1, 0, 0, 0);
        }
        __builtin_amdgcn_s_setprio(0);
        const int kv0 = t * 64;
        if (kv0 + 63 > q0w) {   // causal mask (diagonal region only)
#pragma unroll
            for (int r = 0; r < 16; ++r) {
                int kvg = kv0 + (r & 3) + 8 * (r >> 2) + 4 * hb;
                if (kvg > qg) p0[r] = -3e38f;
                if (kvg + 32 > qg) p1[r] = -3e38f;
            }
        }
        // ---- online softmax, in-register ----
        float pm = -3e38f;
#pragma unroll
        for (int r = 0; r < 16; ++r) pm = fmaxf(pm, fmaxf(p0[r], p1[r]));
        pm = fmaxf(pm, __shfl_xor(pm, 32));
        if (__any(pm > m_raw + 64.f)) {   // defer-max (T13)
            float mn = fmaxf(m_raw, pm);
            float alpha = exp2f((m_raw - mn) * sc2);
            m_raw = mn; mb = mn * sc2;
            l_r *= alpha;
#pragma unroll
            for (int dt = 0; dt < 4; ++dt)
#pragma unroll
                for (int r = 0; r < 16; ++r) o[dt][r] *= alpha;
        }
        float ps = 0.f;
#pragma unroll
        for (int r = 0; r < 16; ++r) {
            p0[r] = exp2f(__builtin_fmaf(p0[r], sc2, -mb));
            p1[r] = exp2f(__builtin_fmaf(p1[r], sc2, -mb));
            ps += p0[r] + p1[r];
        }
        l_r += ps;
        // ---- pack P -> bf16 B-frags (cvt_pk + permlane32_swap) ----
        unsigned int pk0[8], pk1[8];
#pragma unroll
        for (int i = 0; i < 8; ++i) {
            asm("v_cvt_pk_bf16_f32 %0, %1, %2" : "=v"(pk0[i]) : "v"(p0[2 * i]), "v"(p0[2 * i + 1]));
            asm("v_cvt_pk_bf16_f32 %0, %1, %2" : "=v"(pk1[i]) : "v"(p1[2 * i]), "v"(p1[2 * i + 1]));
        }
        uint4 bfr[4];
#pragma unroll
        for (int sg = 0; sg < 2; ++sg) {
            unsigned int x0 = pk0[4 * sg], y0 = pk0[4 * sg + 2];
            asm volatile("v_permlane32_swap_b32 %0, %1" : "+v"(x0), "+v"(y0));
            unsigned int x1 = pk0[4 * sg + 1], y1 = pk0[4 * sg + 3];
            asm volatile("v_permlane32_swap_b32 %0, %1" : "+v"(x1), "+v"(y1));
            bfr[sg] = make_uint4(x0, x1, y0, y1);
            unsigned int x2 = pk1[4 * sg], y2 = pk1[4 * sg + 2];
            asm volatile("v_permlane32_swap_b32 %0, %1" : "+v"(x2), "+v"(y2));
            unsigned int x3 = pk1[4 * sg + 1], y3 = pk1[4 * sg + 3];
            asm volatile("v_permlane32_swap_b32 %0, %1" : "+v"(x3), "+v"(y3));
            bfr[2 + sg] = make_uint4(x2, x3, y2, y3);
        }
        // ---- O^T += V^T * P^T ----
        __builtin_amdgcn_s_setprio(1);
#pragma unroll
        for (int ss = 0; ss < 4; ++ss) {
            short8 pb = __builtin_bit_cast(short8, bfr[ss]);
            int vc = 16 * ss + 8 * hb;
#pragma unroll
            for (int dt = 0; dt < 4; ++dt) {
                short8 vf = *(const short8*)&Vs[cur][dt * 32 + ql][vc];
                o[dt] = __builtin_amdgcn_mfma_f32_32x32x16_bf16(vf, pb, o[dt], 0, 0, 0);
            }
        }
        __builtin_amdgcn_s_setprio(0);
    };

    stageK(0, 0);
    loadV(0);
    writeV(0);
    __syncthreads();

    for (int t = 0; t < nt; ++t) {
        const int cur = t & 1;
        if (t + 1 < nt) { stageK(t + 1, cur ^ 1); loadV(t + 1); }   // async over compute
        if (t * 64 <= q0w_hi + 31)
            compute(t, cur, oh, mh_raw, mh_b, lh, qfh, q0w_hi, qg_hi);
        if (t < nt_lo && t * 64 <= q0w_lo + 31)
            compute(t, cur, ol, ml_raw, ml_b, ll, qfl, q0w_lo, qg_lo);
        if (t + 1 < nt) writeV(cur ^ 1);   // late write (T14)
        __syncthreads();
    }

    // ---- epilogue: per q-tile, combine l across hi/lo halves, normalize, transpose, store ----
    auto epilogue = [&](f32x16 (&o)[4], float l_r, int q0w) {
        l_r += __shfl_xor(l_r, 32);
        float inv_l = 1.f / l_r;
        unsigned int* ep = (unsigned int*)smem + wave * 2176;   // per-wave [32 q][68 dwords]
#pragma unroll
        for (int dt = 0; dt < 4; ++dt)
#pragma unroll
            for (int r = 0; r < 16; r += 2) {
                float a = o[dt][r] * inv_l, c2 = o[dt][r + 1] * inv_l;
                unsigned int pkv;
                asm("v_cvt_pk_bf16_f32 %0, %1, %2" : "=v"(pkv) : "v"(a), "v"(c2));
                ep[ql * 68 + dt * 16 + ((r & 3) >> 1) + 4 * (r >> 2) + 2 * hb] = pkv;
            }
#pragma unroll
        for (int it = 0; it < 8; ++it) {
            int qr = lane >> 1, ch = (lane & 1) * 8 + it;
            uint4 w = *(uint4*)&ep[qr * 68 + ch * 4];
            *(uint4*)(attn_out + (size_t)(kvB + q0w + qr) * 2048 + h * 128 + ch * 8) = w;
        }
    };
    epilogue(oh, lh, q0w_hi);   // wave-private region; within-wave RAW ordered by lgkmcnt
    epilogue(ol, ll, q0w_lo);
}

// ---------------- launcher ----------------

extern "C" void kernel_launch(void* const* d_in, const int* in_sizes, int n_in,
                              void* d_out, int out_size, void* d_ws, size_t ws_size,
                              hipStream_t stream) {
    const float* x     = (const float*)d_in[0];
    const float* W_dkv = (const float*)d_in[1];
    const float* W_dq  = (const float*)d_in[2];
    const float* W_kr  = (const float*)d_in[3];
    const float* W_qc  = (const float*)d_in[4];
    const float* W_qr  = (const float*)d_in[5];
    const float* W_uk  = (const float*)d_in[6];
    const float* W_uv  = (const float*)d_in[7];
    const float* W_o   = (const float*)d_in[8];
    float* out = (float*)d_out;

    size_t off = 0;
    auto alloc = [&](size_t bytes) {
        void* p = (char*)d_ws + off;
        off = (off + bytes + 255) & ~(size_t)255;
        return p;
    };
    unsigned short* xb    = (unsigned short*)alloc((size_t)NTOK * 2048 * 2);
    unsigned short* WcatT = (unsigned short*)alloc((size_t)320 * 2048 * 2);
    unsigned short* WqT   = (unsigned short*)alloc((size_t)2048 * 128 * 2);
    unsigned short* WkT   = (unsigned short*)alloc((size_t)1024 * 128 * 2);
    unsigned short* WuvT  = (unsigned short*)alloc((size_t)16 * 128 * 128 * 2);
    unsigned short* WoT   = (unsigned short*)alloc((size_t)2048 * 2048 * 2);
    unsigned short* g1    = (unsigned short*)alloc((size_t)NTOK * 320 * 2);
    unsigned short* q_all = (unsigned short*)alloc((size_t)NTOK * 2048 * 2);
    unsigned short* k_all = (unsigned short*)alloc((size_t)NTOK * 1024 * 2);
    unsigned short* v_tg  = (unsigned short*)alloc((size_t)32 * 128 * 2048 * 2);
    unsigned short* attn  = (unsigned short*)alloc((size_t)NTOK * 2048 * 2);

    conv_f32_bf16<<<8192, 256, 0, stream>>>(x, xb, NTOK * 2048);
    build_wcat<<<2560, 256, 0, stream>>>(W_dkv, W_dq, W_kr, WcatT);
    build_wq<<<1024, 256, 0, stream>>>(W_qc, W_qr, WqT);
    build_wk<<<512, 256, 0, stream>>>(W_uk, WkT);
    build_wuvT<<<1024, 256, 0, stream>>>(W_uv, WuvT);
    build_wo<<<dim3(32, 32), 256, 0, stream>>>(W_o, WoT);

    // latent GEMM: [4096,2048] x [2048,320] -> g1
    gemm_bf16_kernel<64, unsigned short><<<dim3(5, 32), 256, 0, stream>>>(
        xb, 2048, WcatT, 2048, g1, 320, NTOK, 320, 2048);
    rope_k_kernel<<<NTOK * 32 / 256, 256, 0, stream>>>(g1);

    // per-head projections (K=128)
    gemm_bf16_kernel<128, unsigned short><<<dim3(16, 32), 256, 0, stream>>>(
        g1 + 128, 320, WqT, 128, q_all, 2048, NTOK, 2048, 128);
    gemm_bf16_kernel<128, unsigned short><<<dim3(8, 32), 256, 0, stream>>>(
        g1, 320, WkT, 128, k_all, 1024, NTOK, 1024, 128);
    gemm_vt_kernel<<<dim3(16, 32), 256, 0, stream>>>(WuvT, g1, v_tg);
    rope_q_kernel<<<NTOK * 16 * 32 / 256, 256, 0, stream>>>(q_all);

    // attention: 256 perfectly-balanced blocks (1/CU)
    mla_attn_kernel<<<256, 256, 0, stream>>>(q_all, k_all, g1, v_tg, attn);

    // output projection -> fp32
    gemm_bf16_kernel<128, float><<<dim3(16, 32), 256, 0, stream>>>(
        attn, 2048, WoT, 2048, out, 2048, NTOK, 2048, 2048);
}

// Round 6
// 256.933 us; speedup vs baseline: 1.1051x; 1.1051x over previous
//
#include <hip/hip_runtime.h>
#include <hip/hip_bf16.h>

typedef __attribute__((ext_vector_type(8))) short short8;
typedef __attribute__((ext_vector_type(4))) float f32x4;
typedef __attribute__((ext_vector_type(16))) float f32x16;

#define N_EMBED 2048
#define N_HEAD 16
#define D_KV 128
#define D_C 64
#define D_R 64
#define D_H 128
#define BB 2
#define SS 2048
#define NTOK (BB*SS)          // 4096

__device__ __forceinline__ unsigned short f2bf(float f) {
    unsigned int b = __builtin_bit_cast(unsigned int, f);
    b += 0x7fffu + ((b >> 16) & 1u);
    return (unsigned short)(b >> 16);
}
__device__ __forceinline__ float bf2f(unsigned short u) {
    unsigned int b = ((unsigned int)u) << 16;
    return __builtin_bit_cast(float, b);
}

#define GLOAD_LDS16(gsrc, ldst) __builtin_amdgcn_global_load_lds( \
    (const __attribute__((address_space(1))) void*)(gsrc), \
    (__attribute__((address_space(3))) void*)(ldst), 16, 0, 0)

// ---------------- conversion / layout kernels ----------------

__global__ void conv_f32_bf16(const float* __restrict__ in, unsigned short* __restrict__ out, int n) {
    int i = (blockIdx.x * 256 + threadIdx.x) * 4;
    if (i >= n) return;
    float4 v = *(const float4*)(in + i);
    ushort4 o;
    o.x = f2bf(v.x); o.y = f2bf(v.y); o.z = f2bf(v.z); o.w = f2bf(v.w);
    *(ushort4*)(out + i) = o;
}

// Wcat_T [320][2048]
__global__ void build_wcat(const float* __restrict__ Wdkv, const float* __restrict__ Wdq,
                           const float* __restrict__ Wkr, unsigned short* __restrict__ out) {
    int i = blockIdx.x * 256 + threadIdx.x;
    int n = i >> 11, k = i & 2047;
    float v;
    if (n < 128)      v = Wdkv[k * 128 + n];
    else if (n < 256) v = Wdq[k * 128 + (n - 128)];
    else              v = Wkr[k * 64 + (n - 256)];
    out[i] = f2bf(v);
}

// Wq_T [2048][128]
__global__ void build_wq(const float* __restrict__ Wqc, const float* __restrict__ Wqr,
                         unsigned short* __restrict__ out) {
    int i = blockIdx.x * 256 + threadIdx.x;
    int n = i >> 7, k = i & 127;
    int h = n >> 7, c = n & 127;
    float v = (c < 64) ? Wqc[(h * 128 + k) * 64 + c] : Wqr[(h * 128 + k) * 64 + (c - 64)];
    out[i] = f2bf(v);
}

// Wk_T [1024][128]
__global__ void build_wk(const float* __restrict__ Wuk, unsigned short* __restrict__ out) {
    int i = blockIdx.x * 256 + threadIdx.x;
    int n = i >> 7, k = i & 127;
    int h = n >> 6, c = n & 63;
    out[i] = f2bf(Wuk[(h * 128 + k) * 64 + c]);
}

// WuvT [16][128][128]
__global__ void build_wuvT(const float* __restrict__ Wuv, unsigned short* __restrict__ out) {
    int i = blockIdx.x * 256 + threadIdx.x;
    int h = i >> 14, d = (i >> 7) & 127, k = i & 127;
    out[i] = f2bf(Wuv[(h * 128 + k) * 128 + d]);
}

// Wo_T [2048][2048] via LDS-tiled transpose
__global__ __launch_bounds__(256) void build_wo(const float* __restrict__ Wo, unsigned short* __restrict__ out) {
    __shared__ float tile[64][65];
    const int k0 = blockIdx.x * 64, n0 = blockIdx.y * 64;
    const int tid = threadIdx.x;
    const int tr = tid >> 4, tc = (tid & 15) * 4;
#pragma unroll
    for (int it = 0; it < 4; ++it) {
        int r = it * 16 + tr;
        float4 v = *(const float4*)(Wo + (size_t)(k0 + r) * 2048 + n0 + tc);
        tile[r][tc] = v.x; tile[r][tc + 1] = v.y; tile[r][tc + 2] = v.z; tile[r][tc + 3] = v.w;
    }
    __syncthreads();
#pragma unroll
    for (int it = 0; it < 4; ++it) {
        int r = it * 16 + tr;
        ushort4 o;
        o.x = f2bf(tile[tc][r]); o.y = f2bf(tile[tc + 1][r]);
        o.z = f2bf(tile[tc + 2][r]); o.w = f2bf(tile[tc + 3][r]);
        *(ushort4*)(out + (size_t)(n0 + r) * 2048 + k0 + tc) = o;
    }
}

// ---------------- rope (table-based) ----------------

#define ROPE_COEF (-0.28782313662425575f)  // -ln(10000)/32

__global__ void build_rope(float2* __restrict__ tab) {
    int i = blockIdx.x * 256 + threadIdx.x;   // SS*32
    int pos = i >> 5, j = i & 31;
    float freq = __expf(ROPE_COEF * (float)j);
    float a = (float)pos * freq;
    float s, c;
    __sincosf(a, &s, &c);
    tab[i] = make_float2(c, s);
}

__global__ void rope_k_kernel(unsigned short* __restrict__ g1, const float2* __restrict__ tab) {
    int i = blockIdx.x * 256 + threadIdx.x;   // NTOK*32
    int j = i & 31, row = i >> 5;
    int pos = row & (SS - 1);
    float2 cs = tab[(pos << 5) | j];
    unsigned short* p = g1 + (size_t)row * 320 + 256 + 2 * j;
    float x0 = bf2f(p[0]), x1 = bf2f(p[1]);
    p[0] = f2bf(x0 * cs.x - x1 * cs.y);
    p[1] = f2bf(x0 * cs.y + x1 * cs.x);
}

__global__ void rope_q_kernel(unsigned short* __restrict__ q, const float2* __restrict__ tab) {
    int i = blockIdx.x * 256 + threadIdx.x;   // NTOK*16*32
    int j = i & 31, h = (i >> 5) & 15, row = i >> 9;
    int pos = row & (SS - 1);
    float2 cs = tab[(pos << 5) | j];
    unsigned short* p = q + (size_t)row * 2048 + h * 128 + 64 + 2 * j;
    float x0 = bf2f(p[0]), x1 = bf2f(p[1]);
    p[0] = f2bf(x0 * cs.x - x1 * cs.y);
    p[1] = f2bf(x0 * cs.y + x1 * cs.x);
}

// ---------------- GEMM (2-phase dbuf): C[M,N] = A[M,K] * Bt[N,K]^T ----------------

__device__ __forceinline__ void store_c(float* p, float v) { *p = v; }
__device__ __forceinline__ void store_c(unsigned short* p, float v) { *p = f2bf(v); }

template <int BN, typename CT>
__global__ __launch_bounds__(256) void gemm_bf16_kernel(
    const unsigned short* __restrict__ A, int lda,
    const unsigned short* __restrict__ Bt, int ldb,
    CT* __restrict__ C, int ldc,
    int M, int N, int K) {
    constexpr int BM = 128, BK = 32;
    __shared__ __align__(16) unsigned short As[2][BM][BK];
    __shared__ __align__(16) unsigned short Bs[2][BN][BK];
    constexpr int WN = BN / 2;
    constexpr int FM = 4, FN = WN / 16;
    const int tid = threadIdx.x, wave = tid >> 6, lane = tid & 63;
    const int wr = wave >> 1, wc = wave & 1;
    const int lg = lane >> 4, lr = lane & 15;
    const int m0 = blockIdx.y * BM, n0 = blockIdx.x * BN;

    f32x4 acc[FM][FN] = {};

    auto stage = [&](int k0, int buf) {
#pragma unroll
        for (int it = 0; it < (BM * BK) / 2048; ++it) {
            int e = (tid + it * 256) * 8;
            GLOAD_LDS16(A + (size_t)(m0 + (e >> 5)) * lda + k0 + (e & 31), &As[buf][0][0] + e);
        }
#pragma unroll
        for (int it = 0; it < (BN * BK) / 2048; ++it) {
            int e = (tid + it * 256) * 8;
            GLOAD_LDS16(Bt + (size_t)(n0 + (e >> 5)) * ldb + k0 + (e & 31), &Bs[buf][0][0] + e);
        }
    };

    const int nk = K / BK;
    stage(0, 0);
    __syncthreads();
    for (int t = 0; t < nk; ++t) {
        const int cur = t & 1;
        if (t + 1 < nk) stage((t + 1) * BK, cur ^ 1);   // overlaps compute(t)
        short8 af[FM], bfr[FN];
#pragma unroll
        for (int i = 0; i < FM; i++) af[i] = *(const short8*)&As[cur][wr * 64 + i * 16 + lr][lg * 8];
#pragma unroll
        for (int j = 0; j < FN; j++) bfr[j] = *(const short8*)&Bs[cur][wc * WN + j * 16 + lr][lg * 8];
#pragma unroll
        for (int i = 0; i < FM; i++)
#pragma unroll
            for (int j = 0; j < FN; j++)
                acc[i][j] = __builtin_amdgcn_mfma_f32_16x16x32_bf16(af[i], bfr[j], acc[i][j], 0, 0, 0);
        __syncthreads();   // drains stage(t+1) loads
    }
#pragma unroll
    for (int i = 0; i < FM; i++)
#pragma unroll
        for (int j = 0; j < FN; j++)
#pragma unroll
            for (int r = 0; r < 4; r++) {
                int row = m0 + wr * 64 + i * 16 + lg * 4 + r;
                int col = n0 + wc * WN + j * 16 + lr;
                store_c(&C[(size_t)row * ldc + col], acc[i][j][r]);
            }
}

// Batched GEMM producing transposed V: v_t[bh][d][s]
__global__ __launch_bounds__(256) void gemm_vt_kernel(
    const unsigned short* __restrict__ WuvT,   // [16][128][128]
    const unsigned short* __restrict__ g1,     // [NTOK][320], c_kv cols 0..127
    unsigned short* __restrict__ v_t) {        // [32][128][2048]
    constexpr int BK = 32;
    __shared__ __align__(16) unsigned short As[2][128][BK];
    __shared__ __align__(16) unsigned short Bs[2][128][BK];
    const int tid = threadIdx.x, wave = tid >> 6, lane = tid & 63;
    const int wr = wave >> 1, wc = wave & 1;
    const int lg = lane >> 4, lr = lane & 15;
    const int n0 = blockIdx.x * 128;
    const int bh = blockIdx.y, b = bh >> 4, h = bh & 15;
    const unsigned short* A = WuvT + (size_t)h * 16384;
    const unsigned short* Bt = g1 + (size_t)(b * SS) * 320;
    unsigned short* C = v_t + (size_t)bh * 128 * 2048;

    f32x4 acc[4][4] = {};
    auto stage = [&](int k0, int buf) {
#pragma unroll
        for (int it = 0; it < 2; ++it) {
            int e = (tid + it * 256) * 8;
            GLOAD_LDS16(A + (size_t)(e >> 5) * 128 + k0 + (e & 31), &As[buf][0][0] + e);
        }
#pragma unroll
        for (int it = 0; it < 2; ++it) {
            int e = (tid + it * 256) * 8;
            GLOAD_LDS16(Bt + (size_t)(n0 + (e >> 5)) * 320 + k0 + (e & 31), &Bs[buf][0][0] + e);
        }
    };
    stage(0, 0);
    __syncthreads();
    for (int t = 0; t < 4; ++t) {
        const int cur = t & 1;
        if (t + 1 < 4) stage((t + 1) * BK, cur ^ 1);
        short8 af[4], bfr[4];
#pragma unroll
        for (int i = 0; i < 4; i++) af[i] = *(const short8*)&As[cur][wr * 64 + i * 16 + lr][lg * 8];
#pragma unroll
        for (int j = 0; j < 4; j++) bfr[j] = *(const short8*)&Bs[cur][wc * 64 + j * 16 + lr][lg * 8];
#pragma unroll
        for (int i = 0; i < 4; i++)
#pragma unroll
            for (int j = 0; j < 4; j++)
                acc[i][j] = __builtin_amdgcn_mfma_f32_16x16x32_bf16(af[i], bfr[j], acc[i][j], 0, 0, 0);
        __syncthreads();
    }
#pragma unroll
    for (int i = 0; i < 4; i++)
#pragma unroll
        for (int j = 0; j < 4; j++)
#pragma unroll
            for (int r = 0; r < 4; r++) {
                int row = wr * 64 + i * 16 + lg * 4 + r;
                int col = n0 + wc * 64 + j * 16 + lr;
                store_c(&C[(size_t)row * 2048 + col], acc[i][j][r]);
            }
}

// ---------------- flash attention v6: persistent blocks + LPT work-stealing ----------------
// 512 items = (bh, qb) q-tiles sorted by DESCENDING cost (qb=15 first); grid 512
// persistent blocks grab items via global atomic. Per-item compute = v4 engine:
// 4 waves x 32 q-rows (QT=128), KVT=64, dbuf LDS, 1 barrier/tile, in-reg softmax.
__global__ __launch_bounds__(256, 2) void mla_attn_kernel(
    const unsigned short* __restrict__ q_all,   // [NTOK][2048] roped
    const unsigned short* __restrict__ k_all,   // [NTOK][1024] knope per head
    const unsigned short* __restrict__ g1,      // [NTOK][320], roped k_r at 256
    const unsigned short* __restrict__ v_t,     // [32][128][2048]
    unsigned short* __restrict__ attn_out,      // [NTOK][2048]
    int* __restrict__ counter) {
    __shared__ __align__(16) char smem[69632];
    __shared__ int s_item;
    auto Ks = (unsigned short (*)[64][128])smem;            // [2][64][128], chunk-swizzled
    auto Vs = (unsigned short (*)[128][72])(smem + 32768);  // [2][128][72]

    const int tid = threadIdx.x, wave = tid >> 6, lane = tid & 63;
    const int ql = lane & 31, hb = lane >> 5;
    const float sc2 = 0.12751744f;   // (1/sqrt(128)) * log2(e)
    const int xh = ql & 7;

    for (;;) {
        if (tid == 0) s_item = atomicAdd(counter, 1);
        __syncthreads();                 // publishes s_item; also fences smem reuse
        const int item = s_item;
        if (item >= 512) break;
        const int qb = 15 - (item >> 5);         // LPT: heavy q-tiles first
        const int bh = item & 31;
        const int b = bh >> 4, h = bh & 15;
        const int q0w = qb * 128 + wave * 32;
        const int qg = q0w + ql;
        const int nt = 2 * qb + 2;
        const int kvB = b * SS;

        // Q B-operand frags: col=q (lane-owned), k = 16s + 8*hb + j
        short8 qf[8];
        {
            const unsigned short* qp = q_all + (size_t)(kvB + qg) * 2048 + h * 128 + hb * 8;
#pragma unroll
            for (int ss = 0; ss < 8; ++ss) qf[ss] = *(const short8*)(qp + 16 * ss);
        }

        f32x16 o[4] = {};
        float m_raw = -3e38f, mb = 0.f, l_r = 0.f;
        uint4 vreg[4];

        auto stageK = [&](int t, int bufi) {
            // linear LDS dest (tid*16B), source chunk pre-swizzled: sc = slot ^ (row&7)
#pragma unroll
            for (int it = 0; it < 4; ++it) {
                int r = (tid >> 4) + it * 16;
                int sc = (tid & 15) ^ (r & 7);
                const unsigned short* src = (sc < 8)
                    ? k_all + (size_t)(kvB + t * 64 + r) * 1024 + h * 64 + sc * 8
                    : g1 + (size_t)(kvB + t * 64 + r) * 320 + 256 + (sc - 8) * 8;
                GLOAD_LDS16(src, &Ks[bufi][0][0] + tid * 8 + it * 2048);
            }
        };
        auto loadV = [&](int t) {
#pragma unroll
            for (int it = 0; it < 4; ++it) {
                int e = tid * 8 + it * 2048;
                vreg[it] = *(const uint4*)(v_t + ((size_t)bh * 128 + (e >> 6)) * 2048 + t * 64 + (e & 63));
            }
        };
        auto writeV = [&](int bufi) {
#pragma unroll
            for (int it = 0; it < 4; ++it) {
                int e = tid * 8 + it * 2048;
                *(uint4*)&Vs[bufi][e >> 6][e & 63] = vreg[it];
            }
        };

        stageK(0, 0);
        loadV(0);
        writeV(0);
        __syncthreads();

        for (int t = 0; t < nt; ++t) {
            const int cur = t & 1;
            if (t + 1 < nt) { stageK(t + 1, cur ^ 1); loadV(t + 1); }   // async over compute
            if (t * 64 <= q0w + 31) {
                // ---- S^T = K * Q ----
                f32x16 p0 = {}, p1 = {};
                __builtin_amdgcn_s_setprio(1);
#pragma unroll
                for (int ss = 0; ss < 8; ++ss) {
                    int pc = (((2 * ss + hb) ^ xh) << 3);   // swizzled chunk
                    short8 k0 = *(const short8*)&Ks[cur][ql][pc];
                    short8 k1 = *(const short8*)&Ks[cur][32 + ql][pc];
                    p0 = __builtin_amdgcn_mfma_f32_32x32x16_bf16(k0, qf[ss], p0, 0, 0, 0);
                    p1 = __builtin_amdgcn_mfma_f32_32x32x16_bf16(k1, qf[ss], p1, 0, 0, 0);
                }
                __builtin_amdgcn_s_setprio(0);
                const int kv0 = t * 64;
                if (kv0 + 63 > q0w) {   // causal mask (diagonal region only)
#pragma unroll
                    for (int r = 0; r < 16; ++r) {
                        int kvg = kv0 + (r & 3) + 8 * (r >> 2) + 4 * hb;
                        if (kvg > qg) p0[r] = -3e38f;
                        if (kvg + 32 > qg) p1[r] = -3e38f;
                    }
                }
                // ---- online softmax, in-register ----
                float pm = -3e38f;
#pragma unroll
                for (int r = 0; r < 16; ++r) pm = fmaxf(pm, fmaxf(p0[r], p1[r]));
                pm = fmaxf(pm, __shfl_xor(pm, 32));
                if (__any(pm > m_raw + 64.f)) {   // defer-max (T13)
                    float mn = fmaxf(m_raw, pm);
                    float alpha = exp2f((m_raw - mn) * sc2);
                    m_raw = mn; mb = mn * sc2;
                    l_r *= alpha;
#pragma unroll
                    for (int dt = 0; dt < 4; ++dt)
#pragma unroll
                        for (int r = 0; r < 16; ++r) o[dt][r] *= alpha;
                }
                float ps = 0.f;
#pragma unroll
                for (int r = 0; r < 16; ++r) {
                    p0[r] = exp2f(__builtin_fmaf(p0[r], sc2, -mb));
                    p1[r] = exp2f(__builtin_fmaf(p1[r], sc2, -mb));
                    ps += p0[r] + p1[r];
                }
                l_r += ps;
                // ---- pack P -> bf16 B-frags (cvt_pk + permlane32_swap) ----
                unsigned int pk0[8], pk1[8];
#pragma unroll
                for (int i = 0; i < 8; ++i) {
                    asm("v_cvt_pk_bf16_f32 %0, %1, %2" : "=v"(pk0[i]) : "v"(p0[2 * i]), "v"(p0[2 * i + 1]));
                    asm("v_cvt_pk_bf16_f32 %0, %1, %2" : "=v"(pk1[i]) : "v"(p1[2 * i]), "v"(p1[2 * i + 1]));
                }
                uint4 bfr[4];
#pragma unroll
                for (int sg = 0; sg < 2; ++sg) {
                    unsigned int x0 = pk0[4 * sg], y0 = pk0[4 * sg + 2];
                    asm volatile("v_permlane32_swap_b32 %0, %1" : "+v"(x0), "+v"(y0));
                    unsigned int x1 = pk0[4 * sg + 1], y1 = pk0[4 * sg + 3];
                    asm volatile("v_permlane32_swap_b32 %0, %1" : "+v"(x1), "+v"(y1));
                    bfr[sg] = make_uint4(x0, x1, y0, y1);
                    unsigned int x2 = pk1[4 * sg], y2 = pk1[4 * sg + 2];
                    asm volatile("v_permlane32_swap_b32 %0, %1" : "+v"(x2), "+v"(y2));
                    unsigned int x3 = pk1[4 * sg + 1], y3 = pk1[4 * sg + 3];
                    asm volatile("v_permlane32_swap_b32 %0, %1" : "+v"(x3), "+v"(y3));
                    bfr[2 + sg] = make_uint4(x2, x3, y2, y3);
                }
                // ---- O^T += V^T * P^T ----
                __builtin_amdgcn_s_setprio(1);
#pragma unroll
                for (int ss = 0; ss < 4; ++ss) {
                    short8 pb = __builtin_bit_cast(short8, bfr[ss]);
                    int vc = 16 * ss + 8 * hb;
#pragma unroll
                    for (int dt = 0; dt < 4; ++dt) {
                        short8 vf = *(const short8*)&Vs[cur][dt * 32 + ql][vc];
                        o[dt] = __builtin_amdgcn_mfma_f32_32x32x16_bf16(vf, pb, o[dt], 0, 0, 0);
                    }
                }
                __builtin_amdgcn_s_setprio(0);
            }
            if (t + 1 < nt) writeV(cur ^ 1);   // late write (T14)
            __syncthreads();
        }

        // ---- epilogue: combine l across hi/lo, normalize, transpose via LDS, store ----
        l_r += __shfl_xor(l_r, 32);
        float inv_l = 1.f / l_r;
        unsigned int* ep = (unsigned int*)smem + wave * 2176;   // per-wave [32 q][68 dwords]
#pragma unroll
        for (int dt = 0; dt < 4; ++dt)
#pragma unroll
            for (int r = 0; r < 16; r += 2) {
                float a = o[dt][r] * inv_l, c2 = o[dt][r + 1] * inv_l;
                unsigned int pkv;
                asm("v_cvt_pk_bf16_f32 %0, %1, %2" : "=v"(pkv) : "v"(a), "v"(c2));
                ep[ql * 68 + dt * 16 + ((r & 3) >> 1) + 4 * (r >> 2) + 2 * hb] = pkv;
            }
#pragma unroll
        for (int it = 0; it < 8; ++it) {
            int qr = lane >> 1, ch = (lane & 1) * 8 + it;
            uint4 w = *(uint4*)&ep[qr * 68 + ch * 4];
            *(uint4*)(attn_out + (size_t)(kvB + q0w + qr) * 2048 + h * 128 + ch * 8) = w;
        }
        // next-item barrier at loop top fences ep-region reuse
    }
}

// ---------------- launcher ----------------

extern "C" void kernel_launch(void* const* d_in, const int* in_sizes, int n_in,
                              void* d_out, int out_size, void* d_ws, size_t ws_size,
                              hipStream_t stream) {
    const float* x     = (const float*)d_in[0];
    const float* W_dkv = (const float*)d_in[1];
    const float* W_dq  = (const float*)d_in[2];
    const float* W_kr  = (const float*)d_in[3];
    const float* W_qc  = (const float*)d_in[4];
    const float* W_qr  = (const float*)d_in[5];
    const float* W_uk  = (const float*)d_in[6];
    const float* W_uv  = (const float*)d_in[7];
    const float* W_o   = (const float*)d_in[8];
    float* out = (float*)d_out;

    size_t off = 0;
    auto alloc = [&](size_t bytes) {
        void* p = (char*)d_ws + off;
        off = (off + bytes + 255) & ~(size_t)255;
        return p;
    };
    unsigned short* xb    = (unsigned short*)alloc((size_t)NTOK * 2048 * 2);
    unsigned short* WcatT = (unsigned short*)alloc((size_t)320 * 2048 * 2);
    unsigned short* WqT   = (unsigned short*)alloc((size_t)2048 * 128 * 2);
    unsigned short* WkT   = (unsigned short*)alloc((size_t)1024 * 128 * 2);
    unsigned short* WuvT  = (unsigned short*)alloc((size_t)16 * 128 * 128 * 2);
    unsigned short* WoT   = (unsigned short*)alloc((size_t)2048 * 2048 * 2);
    unsigned short* g1    = (unsigned short*)alloc((size_t)NTOK * 320 * 2);
    unsigned short* q_all = (unsigned short*)alloc((size_t)NTOK * 2048 * 2);
    unsigned short* k_all = (unsigned short*)alloc((size_t)NTOK * 1024 * 2);
    unsigned short* v_tg  = (unsigned short*)alloc((size_t)32 * 128 * 2048 * 2);
    unsigned short* attn  = (unsigned short*)alloc((size_t)NTOK * 2048 * 2);
    float2* rope_tab      = (float2*)alloc((size_t)SS * 32 * sizeof(float2));
    int* counter          = (int*)alloc(256);

    hipMemsetAsync(counter, 0, sizeof(int), stream);

    conv_f32_bf16<<<8192, 256, 0, stream>>>(x, xb, NTOK * 2048);
    build_wcat<<<2560, 256, 0, stream>>>(W_dkv, W_dq, W_kr, WcatT);
    build_wq<<<1024, 256, 0, stream>>>(W_qc, W_qr, WqT);
    build_wk<<<512, 256, 0, stream>>>(W_uk, WkT);
    build_wuvT<<<1024, 256, 0, stream>>>(W_uv, WuvT);
    build_wo<<<dim3(32, 32), 256, 0, stream>>>(W_o, WoT);
    build_rope<<<SS * 32 / 256, 256, 0, stream>>>(rope_tab);

    // latent GEMM: [4096,2048] x [2048,320] -> g1
    gemm_bf16_kernel<64, unsigned short><<<dim3(5, 32), 256, 0, stream>>>(
        xb, 2048, WcatT, 2048, g1, 320, NTOK, 320, 2048);
    rope_k_kernel<<<NTOK * 32 / 256, 256, 0, stream>>>(g1, rope_tab);

    // per-head projections (K=128)
    gemm_bf16_kernel<128, unsigned short><<<dim3(16, 32), 256, 0, stream>>>(
        g1 + 128, 320, WqT, 128, q_all, 2048, NTOK, 2048, 128);
    gemm_bf16_kernel<128, unsigned short><<<dim3(8, 32), 256, 0, stream>>>(
        g1, 320, WkT, 128, k_all, 1024, NTOK, 1024, 128);
    gemm_vt_kernel<<<dim3(16, 32), 256, 0, stream>>>(WuvT, g1, v_tg);
    rope_q_kernel<<<NTOK * 16 * 32 / 256, 256, 0, stream>>>(q_all, rope_tab);

    // attention: persistent work-stealing blocks
    mla_attn_kernel<<<512, 256, 0, stream>>>(q_all, k_all, g1, v_tg, attn, counter);

    // output projection -> fp32
    gemm_bf16_kernel<128, float><<<dim3(16, 32), 256, 0, stream>>>(
        attn, 2048, WoT, 2048, out, 2048, NTOK, 2048, 2048);
}

// Round 7
// 242.985 us; speedup vs baseline: 1.1685x; 1.0574x over previous
//
#include <hip/hip_runtime.h>
#include <hip/hip_bf16.h>

typedef __attribute__((ext_vector_type(8))) short short8;
typedef __attribute__((ext_vector_type(4))) float f32x4;
typedef __attribute__((ext_vector_type(16))) float f32x16;

#define N_EMBED 2048
#define N_HEAD 16
#define D_KV 128
#define D_C 64
#define D_R 64
#define D_H 128
#define BB 2
#define SS 2048
#define NTOK (BB*SS)          // 4096

__device__ __forceinline__ unsigned short f2bf(float f) {
    unsigned int b = __builtin_bit_cast(unsigned int, f);
    b += 0x7fffu + ((b >> 16) & 1u);
    return (unsigned short)(b >> 16);
}
__device__ __forceinline__ float bf2f(unsigned short u) {
    unsigned int b = ((unsigned int)u) << 16;
    return __builtin_bit_cast(float, b);
}

#define GLOAD_LDS16(gsrc, ldst) __builtin_amdgcn_global_load_lds( \
    (const __attribute__((address_space(1))) void*)(gsrc), \
    (__attribute__((address_space(3))) void*)(ldst), 16, 0, 0)

#define ROPE_COEF (-0.28782313662425575f)  // -ln(10000)/32

// ---------------- fused prep kernel: all weight layouts + rope table ----------------
// block ranges: [0,2560) Wcat | [2560,3584) Wq | [3584,4096) Wk | [4096,5120) Wuv
//               [5120,6144) Wo transpose | [6144,6400) rope table
__global__ __launch_bounds__(256) void prep_kernel(
    const float* __restrict__ Wdkv, const float* __restrict__ Wdq, const float* __restrict__ Wkr,
    const float* __restrict__ Wqc, const float* __restrict__ Wqr,
    const float* __restrict__ Wuk, const float* __restrict__ Wuv, const float* __restrict__ Wo,
    unsigned short* __restrict__ WcatT, unsigned short* __restrict__ WqT,
    unsigned short* __restrict__ WkT, unsigned short* __restrict__ WuvT,
    unsigned short* __restrict__ WoT, float2* __restrict__ rope_tab) {
    __shared__ float tile[64][65];
    const int bid = blockIdx.x, tid = threadIdx.x;
    if (bid < 2560) {                       // WcatT [320][2048]
        int i = bid * 256 + tid;
        int n = i >> 11, k = i & 2047;
        float v;
        if (n < 128)      v = Wdkv[k * 128 + n];
        else if (n < 256) v = Wdq[k * 128 + (n - 128)];
        else              v = Wkr[k * 64 + (n - 256)];
        WcatT[i] = f2bf(v);
    } else if (bid < 3584) {                // WqT [2048][128]
        int i = (bid - 2560) * 256 + tid;
        int n = i >> 7, k = i & 127;
        int h = n >> 7, c = n & 127;
        float v = (c < 64) ? Wqc[(h * 128 + k) * 64 + c] : Wqr[(h * 128 + k) * 64 + (c - 64)];
        WqT[i] = f2bf(v);
    } else if (bid < 4096) {                // WkT [1024][128]
        int i = (bid - 3584) * 256 + tid;
        int n = i >> 7, k = i & 127;
        int h = n >> 6, c = n & 63;
        WkT[i] = f2bf(Wuk[(h * 128 + k) * 64 + c]);
    } else if (bid < 5120) {                // WuvT [16][128][128]
        int i = (bid - 4096) * 256 + tid;
        int h = i >> 14, d = (i >> 7) & 127, k = i & 127;
        WuvT[i] = f2bf(Wuv[(h * 128 + k) * 128 + d]);
    } else if (bid < 6144) {                // WoT [2048][2048] tiled transpose
        int tb = bid - 5120;
        const int k0 = (tb & 31) * 64, n0 = (tb >> 5) * 64;
        const int tr = tid >> 4, tc = (tid & 15) * 4;
#pragma unroll
        for (int it = 0; it < 4; ++it) {
            int r = it * 16 + tr;
            float4 v = *(const float4*)(Wo + (size_t)(k0 + r) * 2048 + n0 + tc);
            tile[r][tc] = v.x; tile[r][tc + 1] = v.y; tile[r][tc + 2] = v.z; tile[r][tc + 3] = v.w;
        }
        __syncthreads();
#pragma unroll
        for (int it = 0; it < 4; ++it) {
            int r = it * 16 + tr;
            ushort4 o;
            o.x = f2bf(tile[tc][r]); o.y = f2bf(tile[tc + 1][r]);
            o.z = f2bf(tile[tc + 2][r]); o.w = f2bf(tile[tc + 3][r]);
            *(ushort4*)(WoT + (size_t)(n0 + r) * 2048 + k0 + tc) = o;
        }
    } else {                                // rope table [SS][32]
        int i = (bid - 6144) * 256 + tid;
        int pos = i >> 5, j = i & 31;
        float freq = __expf(ROPE_COEF * (float)j);
        float a = (float)pos * freq;
        float s, c;
        __sincosf(a, &s, &c);
        rope_tab[i] = make_float2(c, s);
    }
}

// ---------------- fused rope (k_rope in g1 + q_rope in q_all) ----------------
__global__ __launch_bounds__(256) void rope_all_kernel(
    unsigned short* __restrict__ g1, unsigned short* __restrict__ q,
    const float2* __restrict__ tab) {
    const int bid = blockIdx.x, tid = threadIdx.x;
    if (bid < 512) {                        // k_rope: NTOK*32
        int i = bid * 256 + tid;
        int j = i & 31, row = i >> 5;
        int pos = row & (SS - 1);
        float2 cs = tab[(pos << 5) | j];
        unsigned short* p = g1 + (size_t)row * 320 + 256 + 2 * j;
        float x0 = bf2f(p[0]), x1 = bf2f(p[1]);
        p[0] = f2bf(x0 * cs.x - x1 * cs.y);
        p[1] = f2bf(x0 * cs.y + x1 * cs.x);
    } else {                                // q_rope: NTOK*16*32
        int i = (bid - 512) * 256 + tid;
        int j = i & 31, h = (i >> 5) & 15, row = i >> 9;
        int pos = row & (SS - 1);
        float2 cs = tab[(pos << 5) | j];
        unsigned short* p = q + (size_t)row * 2048 + h * 128 + 64 + 2 * j;
        float x0 = bf2f(p[0]), x1 = bf2f(p[1]);
        p[0] = f2bf(x0 * cs.x - x1 * cs.y);
        p[1] = f2bf(x0 * cs.y + x1 * cs.x);
    }
}

// ---------------- GEMM (2-phase dbuf): C[M,N] = A[M,K] * Bt[N,K]^T ----------------

__device__ __forceinline__ void store_c(float* p, float v) { *p = v; }
__device__ __forceinline__ void store_c(unsigned short* p, float v) { *p = f2bf(v); }

template <int BN, typename CT, bool SWZ>
__global__ __launch_bounds__(256) void gemm_bf16_kernel(
    const unsigned short* __restrict__ A, int lda,
    const unsigned short* __restrict__ Bt, int ldb,
    CT* __restrict__ C, int ldc,
    int M, int N, int K) {
    constexpr int BM = 128, BK = 32;
    __shared__ __align__(16) unsigned short As[2][BM][BK];
    __shared__ __align__(16) unsigned short Bs[2][BN][BK];
    constexpr int WN = BN / 2;
    constexpr int FM = 4, FN = WN / 16;
    const int tid = threadIdx.x, wave = tid >> 6, lane = tid & 63;
    const int wr = wave >> 1, wc = wave & 1;
    const int lg = lane >> 4, lr = lane & 15;
    int m0, n0;
    if (SWZ) {   // XCD-bijective remap (total blocks % 8 == 0)
        int id = blockIdx.y * gridDim.x + blockIdx.x;
        int tot = gridDim.x * gridDim.y;
        int swz = (id & 7) * (tot >> 3) + (id >> 3);
        n0 = (swz % gridDim.x) * BN;
        m0 = (swz / gridDim.x) * BM;
    } else {
        m0 = blockIdx.y * BM; n0 = blockIdx.x * BN;
    }

    f32x4 acc[FM][FN] = {};

    auto stage = [&](int k0, int buf) {
#pragma unroll
        for (int it = 0; it < (BM * BK) / 2048; ++it) {
            int e = (tid + it * 256) * 8;
            GLOAD_LDS16(A + (size_t)(m0 + (e >> 5)) * lda + k0 + (e & 31), &As[buf][0][0] + e);
        }
#pragma unroll
        for (int it = 0; it < (BN * BK) / 2048; ++it) {
            int e = (tid + it * 256) * 8;
            GLOAD_LDS16(Bt + (size_t)(n0 + (e >> 5)) * ldb + k0 + (e & 31), &Bs[buf][0][0] + e);
        }
    };

    const int nk = K / BK;
    stage(0, 0);
    __syncthreads();
    for (int t = 0; t < nk; ++t) {
        const int cur = t & 1;
        if (t + 1 < nk) stage((t + 1) * BK, cur ^ 1);   // overlaps compute(t)
        short8 af[FM], bfr[FN];
#pragma unroll
        for (int i = 0; i < FM; i++) af[i] = *(const short8*)&As[cur][wr * 64 + i * 16 + lr][lg * 8];
#pragma unroll
        for (int j = 0; j < FN; j++) bfr[j] = *(const short8*)&Bs[cur][wc * WN + j * 16 + lr][lg * 8];
#pragma unroll
        for (int i = 0; i < FM; i++)
#pragma unroll
            for (int j = 0; j < FN; j++)
                acc[i][j] = __builtin_amdgcn_mfma_f32_16x16x32_bf16(af[i], bfr[j], acc[i][j], 0, 0, 0);
        __syncthreads();   // drains stage(t+1) loads
    }
#pragma unroll
    for (int i = 0; i < FM; i++)
#pragma unroll
        for (int j = 0; j < FN; j++)
#pragma unroll
            for (int r = 0; r < 4; r++) {
                int row = m0 + wr * 64 + i * 16 + lg * 4 + r;
                int col = n0 + wc * WN + j * 16 + lr;
                store_c(&C[(size_t)row * ldc + col], acc[i][j][r]);
            }
}

// Latent GEMM with f32 A (conversion folded in): g1[M,320] = x[M,2048] * WcatT^T
__global__ __launch_bounds__(256) void gemm_lat_kernel(
    const float* __restrict__ A,               // [NTOK][2048] f32
    const unsigned short* __restrict__ Bt,     // WcatT [320][2048]
    unsigned short* __restrict__ C) {          // g1 [NTOK][320]
    constexpr int BM = 128, BN = 64, BK = 32, K = 2048;
    __shared__ __align__(16) unsigned short As[2][BM][BK];
    __shared__ __align__(16) unsigned short Bs[2][BN][BK];
    constexpr int WN = BN / 2, FM = 4, FN = WN / 16;
    const int tid = threadIdx.x, wave = tid >> 6, lane = tid & 63;
    const int wr = wave >> 1, wc = wave & 1;
    const int lg = lane >> 4, lr = lane & 15;
    const int m0 = blockIdx.y * BM, n0 = blockIdx.x * BN;

    f32x4 acc[FM][FN] = {};
    const int ar = (tid * 16) >> 5, ac = (tid * 16) & 31;   // this thread's 16-elem A chunk

    float4 a4[4];
    auto loadA = [&](int k0) {
        const float* src = A + (size_t)(m0 + ar) * K + k0 + ac;
#pragma unroll
        for (int i = 0; i < 4; ++i) a4[i] = *(const float4*)(src + i * 4);
    };
    auto writeA = [&](int buf) {
        unsigned int pk[8];
        const float* f = (const float*)a4;
#pragma unroll
        for (int i = 0; i < 8; ++i)
            asm("v_cvt_pk_bf16_f32 %0, %1, %2" : "=v"(pk[i]) : "v"(f[2 * i]), "v"(f[2 * i + 1]));
        *(uint4*)&As[buf][ar][ac]     = make_uint4(pk[0], pk[1], pk[2], pk[3]);
        *(uint4*)&As[buf][ar][ac + 8] = make_uint4(pk[4], pk[5], pk[6], pk[7]);
    };
    auto stageB = [&](int k0, int buf) {
        int e = tid * 8;   // 64*32 = 2048 elems, one pass
        GLOAD_LDS16(Bt + (size_t)(n0 + (e >> 5)) * K + k0 + (e & 31), &Bs[buf][0][0] + e);
    };

    // prologue: tile 0 fully staged
    loadA(0); stageB(0, 0); writeA(0);
    __syncthreads();
    constexpr int nk = K / BK;
    for (int t = 0; t < nk; ++t) {
        const int cur = t & 1;
        if (t + 1 < nk) { loadA((t + 1) * BK); stageB((t + 1) * BK, cur ^ 1); }  // issue early
        short8 af[FM], bfr[FN];
#pragma unroll
        for (int i = 0; i < FM; i++) af[i] = *(const short8*)&As[cur][wr * 64 + i * 16 + lr][lg * 8];
#pragma unroll
        for (int j = 0; j < FN; j++) bfr[j] = *(const short8*)&Bs[cur][wc * WN + j * 16 + lr][lg * 8];
#pragma unroll
        for (int i = 0; i < FM; i++)
#pragma unroll
            for (int j = 0; j < FN; j++)
                acc[i][j] = __builtin_amdgcn_mfma_f32_16x16x32_bf16(af[i], bfr[j], acc[i][j], 0, 0, 0);
        if (t + 1 < nk) writeA(cur ^ 1);   // cvt+ds_write after MFMAs (T14 late-write)
        __syncthreads();
    }
#pragma unroll
    for (int i = 0; i < FM; i++)
#pragma unroll
        for (int j = 0; j < FN; j++)
#pragma unroll
            for (int r = 0; r < 4; r++) {
                int row = m0 + wr * 64 + i * 16 + lg * 4 + r;
                int col = n0 + wc * WN + j * 16 + lr;
                C[(size_t)row * 320 + col] = f2bf(acc[i][j][r]);
            }
}

// Batched GEMM producing transposed V: v_t[bh][d][s]
__global__ __launch_bounds__(256) void gemm_vt_kernel(
    const unsigned short* __restrict__ WuvT,   // [16][128][128]
    const unsigned short* __restrict__ g1,     // [NTOK][320], c_kv cols 0..127
    unsigned short* __restrict__ v_t) {        // [32][128][2048]
    constexpr int BK = 32;
    __shared__ __align__(16) unsigned short As[2][128][BK];
    __shared__ __align__(16) unsigned short Bs[2][128][BK];
    const int tid = threadIdx.x, wave = tid >> 6, lane = tid & 63;
    const int wr = wave >> 1, wc = wave & 1;
    const int lg = lane >> 4, lr = lane & 15;
    const int n0 = blockIdx.x * 128;
    const int bh = blockIdx.y, b = bh >> 4, h = bh & 15;
    const unsigned short* A = WuvT + (size_t)h * 16384;
    const unsigned short* Bt = g1 + (size_t)(b * SS) * 320;
    unsigned short* C = v_t + (size_t)bh * 128 * 2048;

    f32x4 acc[4][4] = {};
    auto stage = [&](int k0, int buf) {
#pragma unroll
        for (int it = 0; it < 2; ++it) {
            int e = (tid + it * 256) * 8;
            GLOAD_LDS16(A + (size_t)(e >> 5) * 128 + k0 + (e & 31), &As[buf][0][0] + e);
        }
#pragma unroll
        for (int it = 0; it < 2; ++it) {
            int e = (tid + it * 256) * 8;
            GLOAD_LDS16(Bt + (size_t)(n0 + (e >> 5)) * 320 + k0 + (e & 31), &Bs[buf][0][0] + e);
        }
    };
    stage(0, 0);
    __syncthreads();
    for (int t = 0; t < 4; ++t) {
        const int cur = t & 1;
        if (t + 1 < 4) stage((t + 1) * BK, cur ^ 1);
        short8 af[4], bfr[4];
#pragma unroll
        for (int i = 0; i < 4; i++) af[i] = *(const short8*)&As[cur][wr * 64 + i * 16 + lr][lg * 8];
#pragma unroll
        for (int j = 0; j < 4; j++) bfr[j] = *(const short8*)&Bs[cur][wc * 64 + j * 16 + lr][lg * 8];
#pragma unroll
        for (int i = 0; i < 4; i++)
#pragma unroll
            for (int j = 0; j < 4; j++)
                acc[i][j] = __builtin_amdgcn_mfma_f32_16x16x32_bf16(af[i], bfr[j], acc[i][j], 0, 0, 0);
        __syncthreads();
    }
#pragma unroll
    for (int i = 0; i < 4; i++)
#pragma unroll
        for (int j = 0; j < 4; j++)
#pragma unroll
            for (int r = 0; r < 4; r++) {
                int row = wr * 64 + i * 16 + lg * 4 + r;
                int col = n0 + wc * 64 + j * 16 + lr;
                store_c(&C[(size_t)row * 2048 + col], acc[i][j][r]);
            }
}

// ---------------- flash attention (R4 exact): 32x32 swapped + balanced pairing ----------------
__global__ __launch_bounds__(256, 2) void mla_attn_kernel(
    const unsigned short* __restrict__ q_all,   // [NTOK][2048] roped
    const unsigned short* __restrict__ k_all,   // [NTOK][1024] knope per head
    const unsigned short* __restrict__ g1,      // [NTOK][320], roped k_r at 256
    const unsigned short* __restrict__ v_t,     // [32][128][2048]
    unsigned short* __restrict__ attn_out) {    // [NTOK][2048]
    __shared__ __align__(16) char smem[69632];
    auto Ks = (unsigned short (*)[64][128])smem;            // [2][64][128], chunk-swizzled
    auto Vs = (unsigned short (*)[128][72])(smem + 32768);  // [2][128][72]

    const int id = blockIdx.x;
    const int xcd = id & 7, s = id >> 3;
    const int half = s >> 5, sl = s & 31;
    const int qb = half ? (sl & 15) : (15 - (sl & 15));
    const int bh = 4 * xcd + 2 * half + (sl >> 4);
    const int b = bh >> 4, h = bh & 15;
    const int q0 = qb * 128;
    const int tid = threadIdx.x, wave = tid >> 6, lane = tid & 63;
    const int ql = lane & 31, hb = lane >> 5;
    const int q0w = q0 + wave * 32;
    const int qg = q0w + ql;
    const int nt = 2 * qb + 2;
    const int kvB = b * SS;
    const float sc2 = 0.12751744f;   // (1/sqrt(128)) * log2(e)
    const int xh = ql & 7;

    short8 qf[8];
    {
        const unsigned short* qp = q_all + (size_t)(kvB + qg) * 2048 + h * 128 + hb * 8;
#pragma unroll
        for (int ss = 0; ss < 8; ++ss) qf[ss] = *(const short8*)(qp + 16 * ss);
    }

    f32x16 o[4] = {};
    float m_raw = -3e38f, mb = 0.f, l_r = 0.f;
    uint4 vreg[4];

    auto stageK = [&](int t, int bufi) {
#pragma unroll
        for (int it = 0; it < 4; ++it) {
            int r = (tid >> 4) + it * 16;
            int sc = (tid & 15) ^ (r & 7);
            const unsigned short* src = (sc < 8)
                ? k_all + (size_t)(kvB + t * 64 + r) * 1024 + h * 64 + sc * 8
                : g1 + (size_t)(kvB + t * 64 + r) * 320 + 256 + (sc - 8) * 8;
            GLOAD_LDS16(src, &Ks[bufi][0][0] + tid * 8 + it * 2048);
        }
    };
    auto loadV = [&](int t) {
#pragma unroll
        for (int it = 0; it < 4; ++it) {
            int e = tid * 8 + it * 2048;
            vreg[it] = *(const uint4*)(v_t + ((size_t)bh * 128 + (e >> 6)) * 2048 + t * 64 + (e & 63));
        }
    };
    auto writeV = [&](int bufi) {
#pragma unroll
        for (int it = 0; it < 4; ++it) {
            int e = tid * 8 + it * 2048;
            *(uint4*)&Vs[bufi][e >> 6][e & 63] = vreg[it];
        }
    };

    stageK(0, 0);
    loadV(0);
    writeV(0);
    __syncthreads();

    for (int t = 0; t < nt; ++t) {
        const int cur = t & 1;
        if (t + 1 < nt) { stageK(t + 1, cur ^ 1); loadV(t + 1); }
        if (t * 64 <= q0w + 31) {
            f32x16 p0 = {}, p1 = {};
            __builtin_amdgcn_s_setprio(1);
#pragma unroll
            for (int ss = 0; ss < 8; ++ss) {
                int pc = (((2 * ss + hb) ^ xh) << 3);
                short8 k0 = *(const short8*)&Ks[cur][ql][pc];
                short8 k1 = *(const short8*)&Ks[cur][32 + ql][pc];
                p0 = __builtin_amdgcn_mfma_f32_32x32x16_bf16(k0, qf[ss], p0, 0, 0, 0);
                p1 = __builtin_amdgcn_mfma_f32_32x32x16_bf16(k1, qf[ss], p1, 0, 0, 0);
            }
            __builtin_amdgcn_s_setprio(0);
            const int kv0 = t * 64;
            if (kv0 + 63 > q0w) {
#pragma unroll
                for (int r = 0; r < 16; ++r) {
                    int kvg = kv0 + (r & 3) + 8 * (r >> 2) + 4 * hb;
                    if (kvg > qg) p0[r] = -3e38f;
                    if (kvg + 32 > qg) p1[r] = -3e38f;
                }
            }
            float pm = -3e38f;
#pragma unroll
            for (int r = 0; r < 16; ++r) pm = fmaxf(pm, fmaxf(p0[r], p1[r]));
            pm = fmaxf(pm, __shfl_xor(pm, 32));
            if (__any(pm > m_raw + 64.f)) {   // defer-max (T13)
                float mn = fmaxf(m_raw, pm);
                float alpha = exp2f((m_raw - mn) * sc2);
                m_raw = mn; mb = mn * sc2;
                l_r *= alpha;
#pragma unroll
                for (int dt = 0; dt < 4; ++dt)
#pragma unroll
                    for (int r = 0; r < 16; ++r) o[dt][r] *= alpha;
            }
            float ps = 0.f;
#pragma unroll
            for (int r = 0; r < 16; ++r) {
                p0[r] = exp2f(__builtin_fmaf(p0[r], sc2, -mb));
                p1[r] = exp2f(__builtin_fmaf(p1[r], sc2, -mb));
                ps += p0[r] + p1[r];
            }
            l_r += ps;
            unsigned int pk0[8], pk1[8];
#pragma unroll
            for (int i = 0; i < 8; ++i) {
                asm("v_cvt_pk_bf16_f32 %0, %1, %2" : "=v"(pk0[i]) : "v"(p0[2 * i]), "v"(p0[2 * i + 1]));
                asm("v_cvt_pk_bf16_f32 %0, %1, %2" : "=v"(pk1[i]) : "v"(p1[2 * i]), "v"(p1[2 * i + 1]));
            }
            uint4 bfr[4];
#pragma unroll
            for (int sg = 0; sg < 2; ++sg) {
                unsigned int x0 = pk0[4 * sg], y0 = pk0[4 * sg + 2];
                asm volatile("v_permlane32_swap_b32 %0, %1" : "+v"(x0), "+v"(y0));
                unsigned int x1 = pk0[4 * sg + 1], y1 = pk0[4 * sg + 3];
                asm volatile("v_permlane32_swap_b32 %0, %1" : "+v"(x1), "+v"(y1));
                bfr[sg] = make_uint4(x0, x1, y0, y1);
                unsigned int x2 = pk1[4 * sg], y2 = pk1[4 * sg + 2];
                asm volatile("v_permlane32_swap_b32 %0, %1" : "+v"(x2), "+v"(y2));
                unsigned int x3 = pk1[4 * sg + 1], y3 = pk1[4 * sg + 3];
                asm volatile("v_permlane32_swap_b32 %0, %1" : "+v"(x3), "+v"(y3));
                bfr[2 + sg] = make_uint4(x2, x3, y2, y3);
            }
            __builtin_amdgcn_s_setprio(1);
#pragma unroll
            for (int ss = 0; ss < 4; ++ss) {
                short8 pb = __builtin_bit_cast(short8, bfr[ss]);
                int vc = 16 * ss + 8 * hb;
#pragma unroll
                for (int dt = 0; dt < 4; ++dt) {
                    short8 vf = *(const short8*)&Vs[cur][dt * 32 + ql][vc];
                    o[dt] = __builtin_amdgcn_mfma_f32_32x32x16_bf16(vf, pb, o[dt], 0, 0, 0);
                }
            }
            __builtin_amdgcn_s_setprio(0);
        }
        if (t + 1 < nt) writeV(cur ^ 1);   // late write (T14)
        __syncthreads();
    }

    l_r += __shfl_xor(l_r, 32);
    float inv_l = 1.f / l_r;
    unsigned int* ep = (unsigned int*)smem + wave * 2176;
#pragma unroll
    for (int dt = 0; dt < 4; ++dt)
#pragma unroll
        for (int r = 0; r < 16; r += 2) {
            float a = o[dt][r] * inv_l, c2 = o[dt][r + 1] * inv_l;
            unsigned int pkv;
            asm("v_cvt_pk_bf16_f32 %0, %1, %2" : "=v"(pkv) : "v"(a), "v"(c2));
            ep[ql * 68 + dt * 16 + ((r & 3) >> 1) + 4 * (r >> 2) + 2 * hb] = pkv;
        }
#pragma unroll
    for (int it = 0; it < 8; ++it) {
        int qr = lane >> 1, ch = (lane & 1) * 8 + it;
        uint4 w = *(uint4*)&ep[qr * 68 + ch * 4];
        *(uint4*)(attn_out + (size_t)(kvB + q0w + qr) * 2048 + h * 128 + ch * 8) = w;
    }
}

// ---------------- launcher ----------------

extern "C" void kernel_launch(void* const* d_in, const int* in_sizes, int n_in,
                              void* d_out, int out_size, void* d_ws, size_t ws_size,
                              hipStream_t stream) {
    const float* x     = (const float*)d_in[0];
    const float* W_dkv = (const float*)d_in[1];
    const float* W_dq  = (const float*)d_in[2];
    const float* W_kr  = (const float*)d_in[3];
    const float* W_qc  = (const float*)d_in[4];
    const float* W_qr  = (const float*)d_in[5];
    const float* W_uk  = (const float*)d_in[6];
    const float* W_uv  = (const float*)d_in[7];
    const float* W_o   = (const float*)d_in[8];
    float* out = (float*)d_out;

    size_t off = 0;
    auto alloc = [&](size_t bytes) {
        void* p = (char*)d_ws + off;
        off = (off + bytes + 255) & ~(size_t)255;
        return p;
    };
    unsigned short* WcatT = (unsigned short*)alloc((size_t)320 * 2048 * 2);
    unsigned short* WqT   = (unsigned short*)alloc((size_t)2048 * 128 * 2);
    unsigned short* WkT   = (unsigned short*)alloc((size_t)1024 * 128 * 2);
    unsigned short* WuvT  = (unsigned short*)alloc((size_t)16 * 128 * 128 * 2);
    unsigned short* WoT   = (unsigned short*)alloc((size_t)2048 * 2048 * 2);
    unsigned short* g1    = (unsigned short*)alloc((size_t)NTOK * 320 * 2);
    unsigned short* q_all = (unsigned short*)alloc((size_t)NTOK * 2048 * 2);
    unsigned short* k_all = (unsigned short*)alloc((size_t)NTOK * 1024 * 2);
    unsigned short* v_tg  = (unsigned short*)alloc((size_t)32 * 128 * 2048 * 2);
    unsigned short* attn  = (unsigned short*)alloc((size_t)NTOK * 2048 * 2);
    float2* rope_tab      = (float2*)alloc((size_t)SS * 32 * sizeof(float2));

    // 1: all weight layouts + rope table
    prep_kernel<<<6400, 256, 0, stream>>>(W_dkv, W_dq, W_kr, W_qc, W_qr, W_uk, W_uv, W_o,
                                          WcatT, WqT, WkT, WuvT, WoT, rope_tab);
    // 2: latent GEMM (f32 A, conversion folded)
    gemm_lat_kernel<<<dim3(5, 32), 256, 0, stream>>>(x, WcatT, g1);
    // 3-5: per-head projections (K=128)
    gemm_bf16_kernel<128, unsigned short, false><<<dim3(16, 32), 256, 0, stream>>>(
        g1 + 128, 320, WqT, 128, q_all, 2048, NTOK, 2048, 128);
    gemm_bf16_kernel<128, unsigned short, false><<<dim3(8, 32), 256, 0, stream>>>(
        g1, 320, WkT, 128, k_all, 1024, NTOK, 1024, 128);
    gemm_vt_kernel<<<dim3(16, 32), 256, 0, stream>>>(WuvT, g1, v_tg);
    // 6: both ropes
    rope_all_kernel<<<512 + 8192, 256, 0, stream>>>(g1, q_all, rope_tab);
    // 7: attention
    mla_attn_kernel<<<512, 256, 0, stream>>>(q_all, k_all, g1, v_tg, attn);
    // 8: output projection -> fp32 (XCD-swizzled)
    gemm_bf16_kernel<128, float, true><<<dim3(16, 32), 256, 0, stream>>>(
        attn, 2048, WoT, 2048, out, 2048, NTOK, 2048, 2048);
}

// Round 8
// 238.338 us; speedup vs baseline: 1.1913x; 1.0195x over previous
//
#include <hip/hip_runtime.h>
#include <hip/hip_bf16.h>

typedef __attribute__((ext_vector_type(8))) short short8;
typedef __attribute__((ext_vector_type(4))) float f32x4;
typedef __attribute__((ext_vector_type(16))) float f32x16;

#define N_EMBED 2048
#define N_HEAD 16
#define D_KV 128
#define D_C 64
#define D_R 64
#define D_H 128
#define BB 2
#define SS 2048
#define NTOK (BB*SS)          // 4096

__device__ __forceinline__ unsigned short f2bf(float f) {
    unsigned int b = __builtin_bit_cast(unsigned int, f);
    b += 0x7fffu + ((b >> 16) & 1u);
    return (unsigned short)(b >> 16);
}
__device__ __forceinline__ float bf2f(unsigned short u) {
    unsigned int b = ((unsigned int)u) << 16;
    return __builtin_bit_cast(float, b);
}

#define GLOAD_LDS16(gsrc, ldst) __builtin_amdgcn_global_load_lds( \
    (const __attribute__((address_space(1))) void*)(gsrc), \
    (__attribute__((address_space(3))) void*)(ldst), 16, 0, 0)

#define ROPE_COEF (-0.28782313662425575f)  // -ln(10000)/32

// ---------------- fused prep kernel: all weight layouts + rope table ----------------
__global__ __launch_bounds__(256) void prep_kernel(
    const float* __restrict__ Wdkv, const float* __restrict__ Wdq, const float* __restrict__ Wkr,
    const float* __restrict__ Wqc, const float* __restrict__ Wqr,
    const float* __restrict__ Wuk, const float* __restrict__ Wuv, const float* __restrict__ Wo,
    unsigned short* __restrict__ WcatT, unsigned short* __restrict__ WqT,
    unsigned short* __restrict__ WkT, unsigned short* __restrict__ WuvT,
    unsigned short* __restrict__ WoT, float2* __restrict__ rope_tab) {
    __shared__ float tile[64][65];
    const int bid = blockIdx.x, tid = threadIdx.x;
    if (bid < 2560) {                       // WcatT [320][2048]
        int i = bid * 256 + tid;
        int n = i >> 11, k = i & 2047;
        float v;
        if (n < 128)      v = Wdkv[k * 128 + n];
        else if (n < 256) v = Wdq[k * 128 + (n - 128)];
        else              v = Wkr[k * 64 + (n - 256)];
        WcatT[i] = f2bf(v);
    } else if (bid < 3584) {                // WqT [2048][128]
        int i = (bid - 2560) * 256 + tid;
        int n = i >> 7, k = i & 127;
        int h = n >> 7, c = n & 127;
        float v = (c < 64) ? Wqc[(h * 128 + k) * 64 + c] : Wqr[(h * 128 + k) * 64 + (c - 64)];
        WqT[i] = f2bf(v);
    } else if (bid < 4096) {                // WkT [1024][128]
        int i = (bid - 3584) * 256 + tid;
        int n = i >> 7, k = i & 127;
        int h = n >> 6, c = n & 63;
        WkT[i] = f2bf(Wuk[(h * 128 + k) * 64 + c]);
    } else if (bid < 5120) {                // WuvT [16][128][128]
        int i = (bid - 4096) * 256 + tid;
        int h = i >> 14, d = (i >> 7) & 127, k = i & 127;
        WuvT[i] = f2bf(Wuv[(h * 128 + k) * 128 + d]);
    } else if (bid < 6144) {                // WoT [2048][2048] tiled transpose
        int tb = bid - 5120;
        const int k0 = (tb & 31) * 64, n0 = (tb >> 5) * 64;
        const int tr = tid >> 4, tc = (tid & 15) * 4;
#pragma unroll
        for (int it = 0; it < 4; ++it) {
            int r = it * 16 + tr;
            float4 v = *(const float4*)(Wo + (size_t)(k0 + r) * 2048 + n0 + tc);
            tile[r][tc] = v.x; tile[r][tc + 1] = v.y; tile[r][tc + 2] = v.z; tile[r][tc + 3] = v.w;
        }
        __syncthreads();
#pragma unroll
        for (int it = 0; it < 4; ++it) {
            int r = it * 16 + tr;
            ushort4 o;
            o.x = f2bf(tile[tc][r]); o.y = f2bf(tile[tc + 1][r]);
            o.z = f2bf(tile[tc + 2][r]); o.w = f2bf(tile[tc + 3][r]);
            *(ushort4*)(WoT + (size_t)(n0 + r) * 2048 + k0 + tc) = o;
        }
    } else {                                // rope table [SS][32]
        int i = (bid - 6144) * 256 + tid;
        int pos = i >> 5, j = i & 31;
        float freq = __expf(ROPE_COEF * (float)j);
        float a = (float)pos * freq;
        float s, c;
        __sincosf(a, &s, &c);
        rope_tab[i] = make_float2(c, s);
    }
}

// ---------------- fused rope ----------------
__global__ __launch_bounds__(256) void rope_all_kernel(
    unsigned short* __restrict__ g1, unsigned short* __restrict__ q,
    const float2* __restrict__ tab) {
    const int bid = blockIdx.x, tid = threadIdx.x;
    if (bid < 512) {                        // k_rope: NTOK*32
        int i = bid * 256 + tid;
        int j = i & 31, row = i >> 5;
        int pos = row & (SS - 1);
        float2 cs = tab[(pos << 5) | j];
        unsigned short* p = g1 + (size_t)row * 320 + 256 + 2 * j;
        float x0 = bf2f(p[0]), x1 = bf2f(p[1]);
        p[0] = f2bf(x0 * cs.x - x1 * cs.y);
        p[1] = f2bf(x0 * cs.y + x1 * cs.x);
    } else {                                // q_rope: NTOK*16*32
        int i = (bid - 512) * 256 + tid;
        int j = i & 31, h = (i >> 5) & 15, row = i >> 9;
        int pos = row & (SS - 1);
        float2 cs = tab[(pos << 5) | j];
        unsigned short* p = q + (size_t)row * 2048 + h * 128 + 64 + 2 * j;
        float x0 = bf2f(p[0]), x1 = bf2f(p[1]);
        p[0] = f2bf(x0 * cs.x - x1 * cs.y);
        p[1] = f2bf(x0 * cs.y + x1 * cs.x);
    }
}

// ---------------- GEMM (2-phase dbuf) ----------------

__device__ __forceinline__ void store_c(float* p, float v) { *p = v; }
__device__ __forceinline__ void store_c(unsigned short* p, float v) { *p = f2bf(v); }

template <int BN, typename CT, bool SWZ>
__global__ __launch_bounds__(256) void gemm_bf16_kernel(
    const unsigned short* __restrict__ A, int lda,
    const unsigned short* __restrict__ Bt, int ldb,
    CT* __restrict__ C, int ldc,
    int M, int N, int K) {
    constexpr int BM = 128, BK = 32;
    __shared__ __align__(16) unsigned short As[2][BM][BK];
    __shared__ __align__(16) unsigned short Bs[2][BN][BK];
    constexpr int WN = BN / 2;
    constexpr int FM = 4, FN = WN / 16;
    const int tid = threadIdx.x, wave = tid >> 6, lane = tid & 63;
    const int wr = wave >> 1, wc = wave & 1;
    const int lg = lane >> 4, lr = lane & 15;
    int m0, n0;
    if (SWZ) {
        int id = blockIdx.y * gridDim.x + blockIdx.x;
        int tot = gridDim.x * gridDim.y;
        int swz = (id & 7) * (tot >> 3) + (id >> 3);
        n0 = (swz % gridDim.x) * BN;
        m0 = (swz / gridDim.x) * BM;
    } else {
        m0 = blockIdx.y * BM; n0 = blockIdx.x * BN;
    }

    f32x4 acc[FM][FN] = {};

    auto stage = [&](int k0, int buf) {
#pragma unroll
        for (int it = 0; it < (BM * BK) / 2048; ++it) {
            int e = (tid + it * 256) * 8;
            GLOAD_LDS16(A + (size_t)(m0 + (e >> 5)) * lda + k0 + (e & 31), &As[buf][0][0] + e);
        }
#pragma unroll
        for (int it = 0; it < (BN * BK) / 2048; ++it) {
            int e = (tid + it * 256) * 8;
            GLOAD_LDS16(Bt + (size_t)(n0 + (e >> 5)) * ldb + k0 + (e & 31), &Bs[buf][0][0] + e);
        }
    };

    const int nk = K / BK;
    stage(0, 0);
    __syncthreads();
    for (int t = 0; t < nk; ++t) {
        const int cur = t & 1;
        if (t + 1 < nk) stage((t + 1) * BK, cur ^ 1);
        short8 af[FM], bfr[FN];
#pragma unroll
        for (int i = 0; i < FM; i++) af[i] = *(const short8*)&As[cur][wr * 64 + i * 16 + lr][lg * 8];
#pragma unroll
        for (int j = 0; j < FN; j++) bfr[j] = *(const short8*)&Bs[cur][wc * WN + j * 16 + lr][lg * 8];
#pragma unroll
        for (int i = 0; i < FM; i++)
#pragma unroll
            for (int j = 0; j < FN; j++)
                acc[i][j] = __builtin_amdgcn_mfma_f32_16x16x32_bf16(af[i], bfr[j], acc[i][j], 0, 0, 0);
        __syncthreads();
    }
#pragma unroll
    for (int i = 0; i < FM; i++)
#pragma unroll
        for (int j = 0; j < FN; j++)
#pragma unroll
            for (int r = 0; r < 4; r++) {
                int row = m0 + wr * 64 + i * 16 + lg * 4 + r;
                int col = n0 + wc * WN + j * 16 + lr;
                store_c(&C[(size_t)row * ldc + col], acc[i][j][r]);
            }
}

// Latent GEMM with f32 A (conversion folded in)
__global__ __launch_bounds__(256) void gemm_lat_kernel(
    const float* __restrict__ A,               // [NTOK][2048] f32
    const unsigned short* __restrict__ Bt,     // WcatT [320][2048]
    unsigned short* __restrict__ C) {          // g1 [NTOK][320]
    constexpr int BM = 128, BN = 64, BK = 32, K = 2048;
    __shared__ __align__(16) unsigned short As[2][BM][BK];
    __shared__ __align__(16) unsigned short Bs[2][BN][BK];
    constexpr int WN = BN / 2, FM = 4, FN = WN / 16;
    const int tid = threadIdx.x, wave = tid >> 6, lane = tid & 63;
    const int wr = wave >> 1, wc = wave & 1;
    const int lg = lane >> 4, lr = lane & 15;
    const int m0 = blockIdx.y * BM, n0 = blockIdx.x * BN;

    f32x4 acc[FM][FN] = {};
    const int ar = (tid * 16) >> 5, ac = (tid * 16) & 31;

    float4 a4[4];
    auto loadA = [&](int k0) {
        const float* src = A + (size_t)(m0 + ar) * K + k0 + ac;
#pragma unroll
        for (int i = 0; i < 4; ++i) a4[i] = *(const float4*)(src + i * 4);
    };
    auto writeA = [&](int buf) {
        unsigned int pk[8];
        const float* f = (const float*)a4;
#pragma unroll
        for (int i = 0; i < 8; ++i)
            asm("v_cvt_pk_bf16_f32 %0, %1, %2" : "=v"(pk[i]) : "v"(f[2 * i]), "v"(f[2 * i + 1]));
        *(uint4*)&As[buf][ar][ac]     = make_uint4(pk[0], pk[1], pk[2], pk[3]);
        *(uint4*)&As[buf][ar][ac + 8] = make_uint4(pk[4], pk[5], pk[6], pk[7]);
    };
    auto stageB = [&](int k0, int buf) {
        int e = tid * 8;
        GLOAD_LDS16(Bt + (size_t)(n0 + (e >> 5)) * K + k0 + (e & 31), &Bs[buf][0][0] + e);
    };

    loadA(0); stageB(0, 0); writeA(0);
    __syncthreads();
    constexpr int nk = K / BK;
    for (int t = 0; t < nk; ++t) {
        const int cur = t & 1;
        if (t + 1 < nk) { loadA((t + 1) * BK); stageB((t + 1) * BK, cur ^ 1); }
        short8 af[FM], bfr[FN];
#pragma unroll
        for (int i = 0; i < FM; i++) af[i] = *(const short8*)&As[cur][wr * 64 + i * 16 + lr][lg * 8];
#pragma unroll
        for (int j = 0; j < FN; j++) bfr[j] = *(const short8*)&Bs[cur][wc * WN + j * 16 + lr][lg * 8];
#pragma unroll
        for (int i = 0; i < FM; i++)
#pragma unroll
            for (int j = 0; j < FN; j++)
                acc[i][j] = __builtin_amdgcn_mfma_f32_16x16x32_bf16(af[i], bfr[j], acc[i][j], 0, 0, 0);
        if (t + 1 < nk) writeA(cur ^ 1);
        __syncthreads();
    }
#pragma unroll
    for (int i = 0; i < FM; i++)
#pragma unroll
        for (int j = 0; j < FN; j++)
#pragma unroll
            for (int r = 0; r < 4; r++) {
                int row = m0 + wr * 64 + i * 16 + lg * 4 + r;
                int col = n0 + wc * WN + j * 16 + lr;
                C[(size_t)row * 320 + col] = f2bf(acc[i][j][r]);
            }
}

// Batched GEMM producing transposed V
__global__ __launch_bounds__(256) void gemm_vt_kernel(
    const unsigned short* __restrict__ WuvT,
    const unsigned short* __restrict__ g1,
    unsigned short* __restrict__ v_t) {
    constexpr int BK = 32;
    __shared__ __align__(16) unsigned short As[2][128][BK];
    __shared__ __align__(16) unsigned short Bs[2][128][BK];
    const int tid = threadIdx.x, wave = tid >> 6, lane = tid & 63;
    const int wr = wave >> 1, wc = wave & 1;
    const int lg = lane >> 4, lr = lane & 15;
    const int n0 = blockIdx.x * 128;
    const int bh = blockIdx.y, b = bh >> 4, h = bh & 15;
    const unsigned short* A = WuvT + (size_t)h * 16384;
    const unsigned short* Bt = g1 + (size_t)(b * SS) * 320;
    unsigned short* C = v_t + (size_t)bh * 128 * 2048;

    f32x4 acc[4][4] = {};
    auto stage = [&](int k0, int buf) {
#pragma unroll
        for (int it = 0; it < 2; ++it) {
            int e = (tid + it * 256) * 8;
            GLOAD_LDS16(A + (size_t)(e >> 5) * 128 + k0 + (e & 31), &As[buf][0][0] + e);
        }
#pragma unroll
        for (int it = 0; it < 2; ++it) {
            int e = (tid + it * 256) * 8;
            GLOAD_LDS16(Bt + (size_t)(n0 + (e >> 5)) * 320 + k0 + (e & 31), &Bs[buf][0][0] + e);
        }
    };
    stage(0, 0);
    __syncthreads();
    for (int t = 0; t < 4; ++t) {
        const int cur = t & 1;
        if (t + 1 < 4) stage((t + 1) * BK, cur ^ 1);
        short8 af[4], bfr[4];
#pragma unroll
        for (int i = 0; i < 4; i++) af[i] = *(const short8*)&As[cur][wr * 64 + i * 16 + lr][lg * 8];
#pragma unroll
        for (int j = 0; j < 4; j++) bfr[j] = *(const short8*)&Bs[cur][wc * 64 + j * 16 + lr][lg * 8];
#pragma unroll
        for (int i = 0; i < 4; i++)
#pragma unroll
            for (int j = 0; j < 4; j++)
                acc[i][j] = __builtin_amdgcn_mfma_f32_16x16x32_bf16(af[i], bfr[j], acc[i][j], 0, 0, 0);
        __syncthreads();
    }
#pragma unroll
    for (int i = 0; i < 4; i++)
#pragma unroll
        for (int j = 0; j < 4; j++)
#pragma unroll
            for (int r = 0; r < 4; r++) {
                int row = wr * 64 + i * 16 + lg * 4 + r;
                int col = n0 + wc * 64 + j * 16 + lr;
                store_c(&C[(size_t)row * 2048 + col], acc[i][j][r]);
            }
}

// ---------------- flash attention v7: split-pair exact balance ----------------
// 512 blocks, EVERY block = exactly 17 kv-tile computes (no dispatch assumptions):
// pair (qb, 15-qb), qb in [0,8). Role A: lo q-tile fully (2qb+2 tiles, direct
// write) then hi q-tile kv tiles [0, x), x = 15-2qb, partial. Role B: hi q-tile
// kv tiles [x, 32-2qb), partial. Hi q-tiles merged by merge_kernel.
__global__ __launch_bounds__(256, 2) void mla_attn_kernel(
    const unsigned short* __restrict__ q_all,   // [NTOK][2048] roped
    const unsigned short* __restrict__ k_all,   // [NTOK][1024] knope per head
    const unsigned short* __restrict__ g1,      // [NTOK][320], roped k_r at 256
    const unsigned short* __restrict__ v_t,     // [32][128][2048]
    unsigned short* __restrict__ attn_out,      // [NTOK][2048]
    float* __restrict__ partO,                  // [256 pair][2 side][128 q][128 d]
    float* __restrict__ partL,                  // [256 pair][2 side][128 q]
    float* __restrict__ partM) {                // same
    __shared__ __align__(16) char smem[69632];
    auto Ks = (unsigned short (*)[64][128])smem;            // [2][64][128], chunk-swizzled
    auto Vs = (unsigned short (*)[128][72])(smem + 32768);  // [2][128][72]

    const int id = blockIdx.x;
    const int xcd = id & 7, loc = id >> 3;
    const int bh = 4 * xcd + (loc >> 4);
    const int s2 = loc & 15;
    const bool roleA = s2 < 8;
    const int qb = roleA ? s2 : s2 - 8;
    const int hiqb = 15 - qb, xsp = 15 - 2 * qb;
    const int pairIdx = bh * 8 + qb;
    const int b = bh >> 4, h = bh & 15;
    const int tid = threadIdx.x, wave = tid >> 6, lane = tid & 63;
    const int ql = lane & 31, hb = lane >> 5;
    const int kvB = b * SS;
    const float sc2 = 0.12751744f;   // (1/sqrt(128)) * log2(e)
    const int xh = ql & 7;

    uint4 vreg[4];
    auto stageK = [&](int t, int bufi) {
#pragma unroll
        for (int it = 0; it < 4; ++it) {
            int r = (tid >> 4) + it * 16;
            int sc = (tid & 15) ^ (r & 7);
            const unsigned short* src = (sc < 8)
                ? k_all + (size_t)(kvB + t * 64 + r) * 1024 + h * 64 + sc * 8
                : g1 + (size_t)(kvB + t * 64 + r) * 320 + 256 + (sc - 8) * 8;
            GLOAD_LDS16(src, &Ks[bufi][0][0] + tid * 8 + it * 2048);
        }
    };
    auto loadV = [&](int t) {
#pragma unroll
        for (int it = 0; it < 4; ++it) {
            int e = tid * 8 + it * 2048;
            vreg[it] = *(const uint4*)(v_t + ((size_t)bh * 128 + (e >> 6)) * 2048 + t * 64 + (e & 63));
        }
    };
    auto writeV = [&](int bufi) {
#pragma unroll
        for (int it = 0; it < 4; ++it) {
            int e = tid * 8 + it * 2048;
            *(uint4*)&Vs[bufi][e >> 6][e & 63] = vreg[it];
        }
    };

    // one q-tile over kv tiles [t0, t0+cnt); direct -> normalized bf16 to attn_out;
    // partial -> f32 O (q-major) + m,l to part buffers at `side`.
    auto run = [&](int q0, int t0, int cnt, bool direct, int side) {
        __syncthreads();   // fence prior smem use (epilogue regions) before restaging
        const int q0w = q0 + wave * 32;
        const int qg = q0w + ql;

        short8 qf[8];
        {
            const unsigned short* qp = q_all + (size_t)(kvB + qg) * 2048 + h * 128 + hb * 8;
#pragma unroll
            for (int ss = 0; ss < 8; ++ss) qf[ss] = *(const short8*)(qp + 16 * ss);
        }
        f32x16 o[4] = {};
        float m_raw = -3e38f, mb = 0.f, l_r = 0.f;

        stageK(t0, 0);
        loadV(t0);
        writeV(0);
        __syncthreads();

        for (int tt = 0; tt < cnt; ++tt) {
            const int t = t0 + tt;
            const int cur = tt & 1;
            if (tt + 1 < cnt) { stageK(t + 1, cur ^ 1); loadV(t + 1); }
            if (t * 64 <= q0w + 31) {
                f32x16 p0 = {}, p1 = {};
                __builtin_amdgcn_s_setprio(1);
#pragma unroll
                for (int ss = 0; ss < 8; ++ss) {
                    int pc = (((2 * ss + hb) ^ xh) << 3);
                    short8 k0 = *(const short8*)&Ks[cur][ql][pc];
                    short8 k1 = *(const short8*)&Ks[cur][32 + ql][pc];
                    p0 = __builtin_amdgcn_mfma_f32_32x32x16_bf16(k0, qf[ss], p0, 0, 0, 0);
                    p1 = __builtin_amdgcn_mfma_f32_32x32x16_bf16(k1, qf[ss], p1, 0, 0, 0);
                }
                __builtin_amdgcn_s_setprio(0);
                const int kv0 = t * 64;
                if (kv0 + 63 > q0w) {
#pragma unroll
                    for (int r = 0; r < 16; ++r) {
                        int kvg = kv0 + (r & 3) + 8 * (r >> 2) + 4 * hb;
                        if (kvg > qg) p0[r] = -3e38f;
                        if (kvg + 32 > qg) p1[r] = -3e38f;
                    }
                }
                float pm = -3e38f;
#pragma unroll
                for (int r = 0; r < 16; ++r) pm = fmaxf(pm, fmaxf(p0[r], p1[r]));
                pm = fmaxf(pm, __shfl_xor(pm, 32));
                if (__any(pm > m_raw + 64.f)) {   // defer-max (T13)
                    float mn = fmaxf(m_raw, pm);
                    float alpha = exp2f((m_raw - mn) * sc2);
                    m_raw = mn; mb = mn * sc2;
                    l_r *= alpha;
#pragma unroll
                    for (int dt = 0; dt < 4; ++dt)
#pragma unroll
                        for (int r = 0; r < 16; ++r) o[dt][r] *= alpha;
                }
                float ps = 0.f;
#pragma unroll
                for (int r = 0; r < 16; ++r) {
                    p0[r] = exp2f(__builtin_fmaf(p0[r], sc2, -mb));
                    p1[r] = exp2f(__builtin_fmaf(p1[r], sc2, -mb));
                    ps += p0[r] + p1[r];
                }
                l_r += ps;
                unsigned int pk0[8], pk1[8];
#pragma unroll
                for (int i = 0; i < 8; ++i) {
                    asm("v_cvt_pk_bf16_f32 %0, %1, %2" : "=v"(pk0[i]) : "v"(p0[2 * i]), "v"(p0[2 * i + 1]));
                    asm("v_cvt_pk_bf16_f32 %0, %1, %2" : "=v"(pk1[i]) : "v"(p1[2 * i]), "v"(p1[2 * i + 1]));
                }
                uint4 bfr[4];
#pragma unroll
                for (int sg = 0; sg < 2; ++sg) {
                    unsigned int x0 = pk0[4 * sg], y0 = pk0[4 * sg + 2];
                    asm volatile("v_permlane32_swap_b32 %0, %1" : "+v"(x0), "+v"(y0));
                    unsigned int x1 = pk0[4 * sg + 1], y1 = pk0[4 * sg + 3];
                    asm volatile("v_permlane32_swap_b32 %0, %1" : "+v"(x1), "+v"(y1));
                    bfr[sg] = make_uint4(x0, x1, y0, y1);
                    unsigned int x2 = pk1[4 * sg], y2 = pk1[4 * sg + 2];
                    asm volatile("v_permlane32_swap_b32 %0, %1" : "+v"(x2), "+v"(y2));
                    unsigned int x3 = pk1[4 * sg + 1], y3 = pk1[4 * sg + 3];
                    asm volatile("v_permlane32_swap_b32 %0, %1" : "+v"(x3), "+v"(y3));
                    bfr[2 + sg] = make_uint4(x2, x3, y2, y3);
                }
                __builtin_amdgcn_s_setprio(1);
#pragma unroll
                for (int ss = 0; ss < 4; ++ss) {
                    short8 pb = __builtin_bit_cast(short8, bfr[ss]);
                    int vc = 16 * ss + 8 * hb;
#pragma unroll
                    for (int dt = 0; dt < 4; ++dt) {
                        short8 vf = *(const short8*)&Vs[cur][dt * 32 + ql][vc];
                        o[dt] = __builtin_amdgcn_mfma_f32_32x32x16_bf16(vf, pb, o[dt], 0, 0, 0);
                    }
                }
                __builtin_amdgcn_s_setprio(0);
            }
            if (tt + 1 < cnt) writeV(cur ^ 1);
            __syncthreads();
        }

        l_r += __shfl_xor(l_r, 32);   // combine hb halves (o already complete per lane)
        if (direct) {
            float inv_l = 1.f / l_r;
            unsigned int* ep = (unsigned int*)smem + wave * 2176;
#pragma unroll
            for (int dt = 0; dt < 4; ++dt)
#pragma unroll
                for (int r = 0; r < 16; r += 2) {
                    float a = o[dt][r] * inv_l, c2 = o[dt][r + 1] * inv_l;
                    unsigned int pkv;
                    asm("v_cvt_pk_bf16_f32 %0, %1, %2" : "=v"(pkv) : "v"(a), "v"(c2));
                    ep[ql * 68 + dt * 16 + ((r & 3) >> 1) + 4 * (r >> 2) + 2 * hb] = pkv;
                }
#pragma unroll
            for (int it = 0; it < 8; ++it) {
                int qr = lane >> 1, ch = (lane & 1) * 8 + it;
                uint4 w = *(uint4*)&ep[qr * 68 + ch * 4];
                *(uint4*)(attn_out + (size_t)(kvB + q0w + qr) * 2048 + h * 128 + ch * 8) = w;
            }
        } else {
            // f32 partial: LDS transpose to q-major [32 q][128 d] per wave
            float* sW = (float*)smem + wave * 4224;   // 32*132 floats = 16896 B/wave
#pragma unroll
            for (int dt = 0; dt < 4; ++dt)
#pragma unroll
                for (int r = 0; r < 16; ++r)
                    sW[ql * 132 + dt * 32 + (r & 3) + 8 * (r >> 2) + 4 * hb] = o[dt][r];
            const size_t pb2 = ((size_t)pairIdx * 2 + side);
            {
                int q = lane >> 1, half = lane & 1;
                const float* src = sW + q * 132 + half * 64;
                float* dst = partO + pb2 * 16384 + (wave * 32 + q) * 128 + half * 64;
#pragma unroll
                for (int j = 0; j < 64; j += 4) *(float4*)(dst + j) = *(const float4*)(src + j);
            }
            if (hb == 0) {
                partL[pb2 * 128 + wave * 32 + ql] = l_r;
                partM[pb2 * 128 + wave * 32 + ql] = m_raw;
            }
        }
    };

    if (roleA) {
        run(qb * 128, 0, 2 * qb + 2, true, 0);        // lo q-tile, full, direct
        run(hiqb * 128, 0, xsp, false, 0);            // hi q-tile, kv [0, x), partial A
    } else {
        run(hiqb * 128, xsp, 17, false, 1);           // hi q-tile, kv [x, 32-2qb), partial B
    }
}

// merge the two partials of each hi q-tile
__global__ __launch_bounds__(256) void merge_kernel(
    const float* __restrict__ partO, const float* __restrict__ partL,
    const float* __restrict__ partM, unsigned short* __restrict__ attn_out) {
    __shared__ float sA[128], sB[128], sI[128];
    const int p = blockIdx.x, tid = threadIdx.x;
    const int bh = p >> 3, qb = p & 7;
    const int b = bh >> 4, h = bh & 15;
    const int q0 = (15 - qb) * 128;
    const float sc2 = 0.12751744f;
    if (tid < 128) {
        float mA = partM[(size_t)(p * 2) * 128 + tid];
        float mB = partM[(size_t)(p * 2 + 1) * 128 + tid];
        float mM = fmaxf(mA, mB);
        float aA = exp2f((mA - mM) * sc2), aB = exp2f((mB - mM) * sc2);
        float lT = aA * partL[(size_t)(p * 2) * 128 + tid] + aB * partL[(size_t)(p * 2 + 1) * 128 + tid];
        sA[tid] = aA; sB[tid] = aB; sI[tid] = 1.f / lT;
    }
    __syncthreads();
    const int q = tid >> 1, half = tid & 1;
    const float aA = sA[q], aB = sB[q], inv = sI[q];
    const float* oA = partO + (size_t)(p * 2) * 16384 + q * 128 + half * 64;
    const float* oB = partO + (size_t)(p * 2 + 1) * 16384 + q * 128 + half * 64;
    unsigned short* dst = attn_out + (size_t)(b * SS + q0 + q) * 2048 + h * 128 + half * 64;
#pragma unroll
    for (int j = 0; j < 64; j += 4) {
        float4 a4 = *(const float4*)(oA + j);
        float4 b4 = *(const float4*)(oB + j);
        ushort4 u;
        u.x = f2bf((aA * a4.x + aB * b4.x) * inv);
        u.y = f2bf((aA * a4.y + aB * b4.y) * inv);
        u.z = f2bf((aA * a4.z + aB * b4.z) * inv);
        u.w = f2bf((aA * a4.w + aB * b4.w) * inv);
        *(ushort4*)(dst + j) = u;
    }
}

// ---------------- launcher ----------------

extern "C" void kernel_launch(void* const* d_in, const int* in_sizes, int n_in,
                              void* d_out, int out_size, void* d_ws, size_t ws_size,
                              hipStream_t stream) {
    const float* x     = (const float*)d_in[0];
    const float* W_dkv = (const float*)d_in[1];
    const float* W_dq  = (const float*)d_in[2];
    const float* W_kr  = (const float*)d_in[3];
    const float* W_qc  = (const float*)d_in[4];
    const float* W_qr  = (const float*)d_in[5];
    const float* W_uk  = (const float*)d_in[6];
    const float* W_uv  = (const float*)d_in[7];
    const float* W_o   = (const float*)d_in[8];
    float* out = (float*)d_out;

    size_t off = 0;
    auto alloc = [&](size_t bytes) {
        void* p = (char*)d_ws + off;
        off = (off + bytes + 255) & ~(size_t)255;
        return p;
    };
    unsigned short* WcatT = (unsigned short*)alloc((size_t)320 * 2048 * 2);
    unsigned short* WqT   = (unsigned short*)alloc((size_t)2048 * 128 * 2);
    unsigned short* WkT   = (unsigned short*)alloc((size_t)1024 * 128 * 2);
    unsigned short* WuvT  = (unsigned short*)alloc((size_t)16 * 128 * 128 * 2);
    unsigned short* WoT   = (unsigned short*)alloc((size_t)2048 * 2048 * 2);
    unsigned short* g1    = (unsigned short*)alloc((size_t)NTOK * 320 * 2);
    unsigned short* q_all = (unsigned short*)alloc((size_t)NTOK * 2048 * 2);
    unsigned short* k_all = (unsigned short*)alloc((size_t)NTOK * 1024 * 2);
    unsigned short* v_tg  = (unsigned short*)alloc((size_t)32 * 128 * 2048 * 2);
    unsigned short* attn  = (unsigned short*)alloc((size_t)NTOK * 2048 * 2);
    float2* rope_tab      = (float2*)alloc((size_t)SS * 32 * sizeof(float2));
    float* partO          = (float*)alloc((size_t)256 * 2 * 16384 * 4);
    float* partL          = (float*)alloc((size_t)256 * 2 * 128 * 4);
    float* partM          = (float*)alloc((size_t)256 * 2 * 128 * 4);

    // 1: all weight layouts + rope table
    prep_kernel<<<6400, 256, 0, stream>>>(W_dkv, W_dq, W_kr, W_qc, W_qr, W_uk, W_uv, W_o,
                                          WcatT, WqT, WkT, WuvT, WoT, rope_tab);
    // 2: latent GEMM (f32 A, conversion folded)
    gemm_lat_kernel<<<dim3(5, 32), 256, 0, stream>>>(x, WcatT, g1);
    // 3-5: per-head projections (K=128)
    gemm_bf16_kernel<128, unsigned short, false><<<dim3(16, 32), 256, 0, stream>>>(
        g1 + 128, 320, WqT, 128, q_all, 2048, NTOK, 2048, 128);
    gemm_bf16_kernel<128, unsigned short, false><<<dim3(8, 32), 256, 0, stream>>>(
        g1, 320, WkT, 128, k_all, 1024, NTOK, 1024, 128);
    gemm_vt_kernel<<<dim3(16, 32), 256, 0, stream>>>(WuvT, g1, v_tg);
    // 6: both ropes
    rope_all_kernel<<<512 + 8192, 256, 0, stream>>>(g1, q_all, rope_tab);
    // 7: attention (split-pair balanced) + merge
    mla_attn_kernel<<<512, 256, 0, stream>>>(q_all, k_all, g1, v_tg, attn, partO, partL, partM);
    merge_kernel<<<256, 256, 0, stream>>>(partO, partL, partM, attn);
    // 8: output projection -> fp32 (XCD-swizzled)
    gemm_bf16_kernel<128, float, true><<<dim3(16, 32), 256, 0, stream>>>(
        attn, 2048, WoT, 2048, out, 2048, NTOK, 2048, 2048);
}